// Round 3
// baseline (18995.178 us; speedup 1.0000x reference)
//
#include <hip/hip_runtime.h>
#include <cstdint>
#include <cstddef>

// ---------------------------------------------------------------------------
// PointNet++ SA module (multi-scale grouping) with attention gate.
// B=16, N=4096, C_IN=64, NPOINT=1024, radii (0.2,0.4), nsamples (32,64),
// MLPs ((64,64,128),(64,64,128)), C_TOTAL=256.
// Dtypes (established rounds 1-2): ALL INPUTS float32; OUTPUT float32
// (the harness's threshold is bf16-scaled, but the buffer is f32 — round 2's
// >1.0 absmax on a [0,1]-bounded output proved the buffer isn't bf16).
// Index-selection paths (FPS argmax, ball query) use non-contracted f32
// arithmetic to bit-match the np f32 reference.
// ---------------------------------------------------------------------------

constexpr int B_ = 16, N_ = 4096, S_ = 1024;
constexpr int WT_G = 67*64 + 64*64 + 128*64 + 64 + 64 + 128; // 16832 floats/group

// workspace layout in 4-byte units (total ~7.7 MB)
constexpr int WS_XYZF = 0;                       // float4[B*N]  (xyz padded)
constexpr int WS_NXYZ = B_*N_*4;                 // float[B*S*3] (new_xyz f32)
constexpr int WS_ATT  = WS_NXYZ + B_*S_*3;       // float[B*256] (attention gate)
constexpr int WS_WT   = WS_ATT + B_*256;         // float[2*WT_G] (transposed weights+biases)
constexpr int WS_IDX0 = WS_WT + 2*WT_G;          // int[B*S*32]
constexpr int WS_IDX1 = WS_IDX0 + B_*S_*32;      // int[B*S*64]

// ---------------------------------------------------------------------------
// K0: xyz -> float4 padding; weights transposed to [cin][cout] so the MLP
// kernel's weight reads are wave-uniform (s_load broadcast).
// ---------------------------------------------------------------------------
__global__ __launch_bounds__(256) void convert_kernel(
    const float* __restrict__ xyz,
    const float* __restrict__ w00, const float* __restrict__ w01,
    const float* __restrict__ w02, const float* __restrict__ b00,
    const float* __restrict__ b01, const float* __restrict__ b02,
    const float* __restrict__ w10, const float* __restrict__ w11,
    const float* __restrict__ w12, const float* __restrict__ b10,
    const float* __restrict__ b11, const float* __restrict__ b12,
    float4* __restrict__ xyzf, float* __restrict__ wt) {
  int id = blockIdx.x * 256 + threadIdx.x;
  if (id < B_*N_) {
    float4 v;
    v.x = xyz[id*3+0]; v.y = xyz[id*3+1]; v.z = xyz[id*3+2]; v.w = 0.f;
    xyzf[id] = v;
    return;
  }
  int wid = id - B_*N_;
  if (wid >= 2*WT_G) return;
  int g = wid / WT_G, r = wid % WT_G;
  float val;
  if (r < 4288) {                    // layer0: w (64,67) -> wt0[c*64+o]
    int c = r >> 6, o = r & 63;
    val = (g ? w10 : w00)[o*67 + c];
  } else if (r < 8384) {             // layer1: w (64,64) -> wt1[c*64+o]
    int rr = r - 4288; int c = rr >> 6, o = rr & 63;
    val = (g ? w11 : w01)[o*64 + c];
  } else if (r < 16576) {            // layer2: w (128,64) -> wt2[c*128+o]
    int rr = r - 8384; int c = rr >> 7, o = rr & 127;
    val = (g ? w12 : w02)[o*64 + c];
  } else {                           // biases: b0(64), b1(64), b2(128)
    int rr = r - 16576;
    val = (rr < 64)  ? (g ? b10 : b00)[rr]
        : (rr < 128) ? (g ? b11 : b01)[rr - 64]
                     : (g ? b12 : b02)[rr - 128];
  }
  wt[g*WT_G + r] = val;
}

// ---------------------------------------------------------------------------
// K1: furthest point sampling. One block per batch; 512 threads x 8 points in
// registers; LDS mirror of xyz for broadcasting the selected point.
// Replicates np exactly: d = ((dx*dx+dy*dy)+dz*dz) f32 no-FMA, running min,
// argmax with smallest-index tie-break. Writes new_xyz (f32 ws + f32 out).
// ---------------------------------------------------------------------------
__global__ __launch_bounds__(512) void fps_kernel(const float4* __restrict__ xyzf,
    float* __restrict__ nxyz, float* __restrict__ out_nxyz) {
  constexpr int PPT = 8;
  __shared__ float sx[N_*3];
  __shared__ float redv[8];
  __shared__ int   redi[8];
  __shared__ int   sel;
  const int b = blockIdx.x, t = threadIdx.x;
  const float4* xb = xyzf + b * N_;
  float px[PPT], py[PPT], pz[PPT], m[PPT];
#pragma unroll
  for (int p = 0; p < PPT; ++p) {
    int idx = t * PPT + p;
    float4 v = xb[idx];
    px[p] = v.x; py[p] = v.y; pz[p] = v.z; m[p] = 1e10f;
    sx[idx*3+0] = v.x; sx[idx*3+1] = v.y; sx[idx*3+2] = v.z;
  }
  if (t == 0) {  // first sampled index is 0 (matches reference)
    float4 v = xb[0];
    int o = b * S_ * 3;
    nxyz[o] = v.x; nxyz[o+1] = v.y; nxyz[o+2] = v.z;
    out_nxyz[o] = v.x; out_nxyz[o+1] = v.y; out_nxyz[o+2] = v.z;
  }
  __syncthreads();
  int cur = 0;
  for (int i = 1; i < S_; ++i) {
    float lx = sx[cur*3], ly = sx[cur*3+1], lz = sx[cur*3+2];
    float bv = -1.f; int bi = 0;
#pragma unroll
    for (int p = 0; p < PPT; ++p) {
      float dx = __fsub_rn(px[p], lx), dy = __fsub_rn(py[p], ly), dz = __fsub_rn(pz[p], lz);
      float d = __fadd_rn(__fadd_rn(__fmul_rn(dx,dx), __fmul_rn(dy,dy)), __fmul_rn(dz,dz));
      m[p] = fminf(m[p], d);
      if (m[p] > bv) { bv = m[p]; bi = t * PPT + p; }  // strict > keeps smallest idx
    }
#pragma unroll
    for (int off = 32; off >= 1; off >>= 1) {
      float ov = __shfl_down(bv, off);
      int   oi = __shfl_down(bi, off);
      if (ov > bv || (ov == bv && oi < bi)) { bv = ov; bi = oi; }
    }
    if ((t & 63) == 0) { redv[t >> 6] = bv; redi[t >> 6] = bi; }
    __syncthreads();
    if (t == 0) {
      float fv = redv[0]; int fi = redi[0];
#pragma unroll
      for (int w = 1; w < 8; ++w)
        if (redv[w] > fv || (redv[w] == fv && redi[w] < fi)) { fv = redv[w]; fi = redi[w]; }
      sel = fi;
      float nx = sx[fi*3], ny = sx[fi*3+1], nz = sx[fi*3+2];
      int o = (b * S_ + i) * 3;
      nxyz[o] = nx; nxyz[o+1] = ny; nxyz[o+2] = nz;
      out_nxyz[o] = nx; out_nxyz[o+1] = ny; out_nxyz[o+2] = nz;
    }
    __syncthreads();
    cur = sel;
  }
}

// ---------------------------------------------------------------------------
// K2: attention gate. att[b,c] = sigmoid(sum_k att_in[b,k]*w_att[k,c]+b_att[c]),
// att_in[b, d*1024+s] = new_xyz[b,s,d]. One block/batch, thread = channel.
// ---------------------------------------------------------------------------
__global__ __launch_bounds__(256) void att_kernel(const float* __restrict__ nxyz,
    const float* __restrict__ w_att, const float* __restrict__ b_att,
    float* __restrict__ att) {
  __shared__ float ai[3 * S_];
  int b = blockIdx.x, t = threadIdx.x;
  for (int k = t; k < 3 * S_; k += 256) {
    int d = k >> 10, s = k & 1023;
    ai[k] = nxyz[(b * S_ + s) * 3 + d];
  }
  __syncthreads();
  float acc = b_att[t];
#pragma unroll 8
  for (int k = 0; k < 3 * S_; ++k)
    acc = fmaf(ai[k], w_att[k * 256 + t], acc);
  att[b * 256 + t] = 1.f / (1.f + expf(-acc));
}

// ---------------------------------------------------------------------------
// K3: ball query. One wave per center; ballot + prefix popcount preserves
// ascending-index order; pad with first hit (center itself always hits).
// ---------------------------------------------------------------------------
template<int NS>
__global__ __launch_bounds__(256) void ballq_kernel(const float4* __restrict__ xyzf,
    const float* __restrict__ nxyz, int* __restrict__ idxbuf, float r2) {
  int lane = threadIdx.x & 63;
  int cid = blockIdx.x * 4 + (threadIdx.x >> 6);
  int b = cid >> 10;
  float cx = nxyz[cid*3], cy = nxyz[cid*3+1], cz = nxyz[cid*3+2];
  const float4* xb = xyzf + b * N_;
  int cnt = 0, first = 0;
  for (int base = 0; base < N_; base += 64) {
    float4 P = xb[base + lane];
    float dx = __fsub_rn(cx, P.x), dy = __fsub_rn(cy, P.y), dz = __fsub_rn(cz, P.z);
    float d2 = __fadd_rn(__fadd_rn(__fmul_rn(dx,dx), __fmul_rn(dy,dy)), __fmul_rn(dz,dz));
    bool hit = d2 < r2;
    unsigned long long mask = __ballot(hit);
    if (cnt == 0 && mask != 0ull) first = base + (int)__builtin_ctzll(mask);
    if (hit) {
      int pos = cnt + (int)__popcll(mask & ((1ull << lane) - 1ull));
      if (pos < NS) idxbuf[cid * NS + pos] = base + lane;
    }
    cnt += (int)__popcll(mask);
    if (cnt >= NS) break;
  }
  if (cnt < NS)
    for (int p2 = cnt + lane; p2 < NS; p2 += 64) idxbuf[cid * NS + p2] = first;
}

// ---------------------------------------------------------------------------
// K4: fused group + 3-layer MLP + ReLU + maxpool + attention scale + store.
// One wave per block. NS=64: 1 center/wave; NS=32: 2 centers/wave.
// Lane = sample column. Activations ping-pong in LDS; 16-accumulator register
// blocking amortizes LDS reads 16x; weights are wave-uniform f32 (s_load).
// ---------------------------------------------------------------------------
template<int NS>
__global__ __launch_bounds__(64) void mlp_kernel(
    const float4* __restrict__ xyzf, const float* __restrict__ feats,
    const float* __restrict__ nxyz, const float* __restrict__ att,
    const int* __restrict__ idxbuf, const float* __restrict__ wt,
    float* __restrict__ outf, int g) {
  constexpr int NCEN = 64 / NS;   // centers per wave
  constexpr int OPL  = 128 / NS;  // output channels per lane at store
  __shared__ float bufA[67 * 64];
  __shared__ float bufB[64 * 64];
  __shared__ float maxbuf[NCEN * 128];
  const int lane = threadIdx.x;
  const int half = lane / NS;
  const int j = lane % NS;
  const int cid = blockIdx.x * NCEN + half;
  const int b = cid >> 10, s = cid & 1023;

  // ---- gather: rel-xyz (3 rows) + features (64 rows) into bufA[c][lane] ----
  int p = idxbuf[cid * NS + j];
  float4 P = xyzf[b * N_ + p];
  bufA[0*64 + lane] = __fsub_rn(P.x, nxyz[cid*3+0]);
  bufA[1*64 + lane] = __fsub_rn(P.y, nxyz[cid*3+1]);
  bufA[2*64 + lane] = __fsub_rn(P.z, nxyz[cid*3+2]);
  const float4* f4 = (const float4*)(feats + (size_t)(b * N_ + p) * 64);
#pragma unroll
  for (int q = 0; q < 16; ++q) {
    float4 u = f4[q];
    bufA[(3+q*4+0)*64+lane] = u.x;
    bufA[(3+q*4+1)*64+lane] = u.y;
    bufA[(3+q*4+2)*64+lane] = u.z;
    bufA[(3+q*4+3)*64+lane] = u.w;
  }
  __syncthreads();
  const float* w0  = wt;                 // [67][64]
  const float* w1  = wt + 67*64;         // [64][64]
  const float* w2  = w1 + 64*64;         // [64][128]
  const float* bb0 = w2 + 64*128;
  const float* bb1 = bb0 + 64;
  const float* bb2 = bb1 + 64;

  // ---- layer 1: 67 -> 64, bufA -> bufB ----
  for (int ob = 0; ob < 4; ++ob) {
    float acc[16];
#pragma unroll
    for (int oi = 0; oi < 16; ++oi) acc[oi] = bb0[ob*16 + oi];
#pragma unroll
    for (int c = 0; c < 67; ++c) {
      float xv = bufA[c*64 + lane];
#pragma unroll
      for (int oi = 0; oi < 16; ++oi) acc[oi] = fmaf(w0[c*64 + ob*16 + oi], xv, acc[oi]);
    }
#pragma unroll
    for (int oi = 0; oi < 16; ++oi) bufB[(ob*16+oi)*64 + lane] = fmaxf(acc[oi], 0.f);
  }
  __syncthreads();

  // ---- layer 2: 64 -> 64, bufB -> bufA ----
  for (int ob = 0; ob < 4; ++ob) {
    float acc[16];
#pragma unroll
    for (int oi = 0; oi < 16; ++oi) acc[oi] = bb1[ob*16 + oi];
#pragma unroll
    for (int c = 0; c < 64; ++c) {
      float yv = bufB[c*64 + lane];
#pragma unroll
      for (int oi = 0; oi < 16; ++oi) acc[oi] = fmaf(w1[c*64 + ob*16 + oi], yv, acc[oi]);
    }
#pragma unroll
    for (int oi = 0; oi < 16; ++oi) bufA[(ob*16+oi)*64 + lane] = fmaxf(acc[oi], 0.f);
  }
  __syncthreads();

  // ---- layer 3: 64 -> 128, fused maxpool over samples (cross-lane) ----
  for (int ob = 0; ob < 8; ++ob) {
    float acc[16];
#pragma unroll
    for (int oi = 0; oi < 16; ++oi) acc[oi] = bb2[ob*16 + oi];
#pragma unroll
    for (int c = 0; c < 64; ++c) {
      float yv = bufA[c*64 + lane];
#pragma unroll
      for (int oi = 0; oi < 16; ++oi) acc[oi] = fmaf(w2[c*128 + ob*16 + oi], yv, acc[oi]);
    }
#pragma unroll
    for (int oi = 0; oi < 16; ++oi) {
      float v = fmaxf(acc[oi], 0.f);
#pragma unroll
      for (int d = NS/2; d >= 1; d >>= 1) v = fmaxf(v, __shfl_xor(v, d));
      if (j == 0) maxbuf[half*128 + ob*16 + oi] = v;
    }
  }
  __syncthreads();

  // ---- attention scale + f32 store: out[b, g*128+o, s] ----
#pragma unroll
  for (int k = 0; k < OPL; ++k) {
    int o = k * NS + j;
    float v = maxbuf[half*128 + o] * att[b*256 + g*128 + o];
    outf[((size_t)(b*256 + g*128 + o)) * 1024 + s] = v;
  }
}

// ---------------------------------------------------------------------------
extern "C" void kernel_launch(void* const* d_in, const int* in_sizes, int n_in,
                              void* d_out, int out_size, void* d_ws, size_t ws_size,
                              hipStream_t stream) {
  const float* xyz   = (const float*)d_in[0];
  const float* feats = (const float*)d_in[1];
  const float* w_att = (const float*)d_in[2];
  const float* b_att = (const float*)d_in[3];
  const float* w00 = (const float*)d_in[4];
  const float* b00 = (const float*)d_in[5];
  const float* w01 = (const float*)d_in[6];
  const float* b01 = (const float*)d_in[7];
  const float* w02 = (const float*)d_in[8];
  const float* b02 = (const float*)d_in[9];
  const float* w10 = (const float*)d_in[10];
  const float* b10 = (const float*)d_in[11];
  const float* w11 = (const float*)d_in[12];
  const float* b11 = (const float*)d_in[13];
  const float* w12 = (const float*)d_in[14];
  const float* b12 = (const float*)d_in[15];

  float* wsf = (float*)d_ws;
  int*   wsi = (int*)d_ws;
  float4* xyzf = (float4*)(wsf + WS_XYZF);
  float* nxyz  = wsf + WS_NXYZ;
  float* att   = wsf + WS_ATT;
  float* wt    = wsf + WS_WT;
  int* idx0 = wsi + WS_IDX0;
  int* idx1 = wsi + WS_IDX1;

  float* out  = (float*)d_out;
  float* outf = out + B_ * S_ * 3;  // features section after new_xyz

  int cvt_total = B_*N_ + 2*WT_G;
  hipLaunchKernelGGL(convert_kernel, dim3((cvt_total + 255) / 256), dim3(256), 0, stream,
                     xyz, w00, w01, w02, b00, b01, b02, w10, w11, w12, b10, b11, b12,
                     xyzf, wt);
  hipLaunchKernelGGL(fps_kernel, dim3(B_), dim3(512), 0, stream, xyzf, nxyz, out);
  hipLaunchKernelGGL(att_kernel, dim3(B_), dim3(256), 0, stream, nxyz, w_att, b_att, att);
  hipLaunchKernelGGL((ballq_kernel<32>), dim3(B_*S_/4), dim3(256), 0, stream,
                     xyzf, nxyz, idx0, (float)(0.2 * 0.2));
  hipLaunchKernelGGL((ballq_kernel<64>), dim3(B_*S_/4), dim3(256), 0, stream,
                     xyzf, nxyz, idx1, (float)(0.4 * 0.4));
  hipLaunchKernelGGL((mlp_kernel<32>), dim3(B_*S_/2), dim3(64), 0, stream,
                     xyzf, feats, nxyz, att, idx0, wt, outf, 0);
  hipLaunchKernelGGL((mlp_kernel<64>), dim3(B_*S_), dim3(64), 0, stream,
                     xyzf, feats, nxyz, att, idx1, wt + WT_G, outf, 1);
}

// Round 4
// 2451.510 us; speedup vs baseline: 7.7484x; 7.7484x over previous
//
#include <hip/hip_runtime.h>
#include <cstdint>
#include <cstddef>

// ---------------------------------------------------------------------------
// PointNet++ SA module (multi-scale grouping) with attention gate.
// B=16, N=4096, C_IN=64, NPOINT=1024, radii (0.2,0.4), nsamples (32,64),
// MLPs ((64,64,128),(64,64,128)), C_TOTAL=256. Inputs f32, output f32.
// Round 4: GEMM-tiled MLP kernel (256 thr, 128-column tile, register tiles,
// single in-place LDS activation buffer). FPS/ballq stay bit-exact vs np.
// ---------------------------------------------------------------------------

constexpr int B_ = 16, N_ = 4096, S_ = 1024;
constexpr int WT_G = 67*64 + 64*64 + 128*64 + 64 + 64 + 128; // 16832 floats/group

// workspace layout in 4-byte units (total ~7.7 MB)
constexpr int WS_XYZF = 0;                       // float4[B*N]  (xyz padded)
constexpr int WS_NXYZ = B_*N_*4;                 // float[B*S*3] (new_xyz f32)
constexpr int WS_ATT  = WS_NXYZ + B_*S_*3;       // float[B*256] (attention gate)
constexpr int WS_WT   = WS_ATT + B_*256;         // float[2*WT_G]
constexpr int WS_IDX0 = WS_WT + 2*WT_G;          // int[B*S*32]
constexpr int WS_IDX1 = WS_IDX0 + B_*S_*32;      // int[B*S*64]

// ---------------------------------------------------------------------------
// K0: xyz -> float4 padding; weights transposed to [cin][cout].
// ---------------------------------------------------------------------------
__global__ __launch_bounds__(256) void convert_kernel(
    const float* __restrict__ xyz,
    const float* __restrict__ w00, const float* __restrict__ w01,
    const float* __restrict__ w02, const float* __restrict__ b00,
    const float* __restrict__ b01, const float* __restrict__ b02,
    const float* __restrict__ w10, const float* __restrict__ w11,
    const float* __restrict__ w12, const float* __restrict__ b10,
    const float* __restrict__ b11, const float* __restrict__ b12,
    float4* __restrict__ xyzf, float* __restrict__ wt) {
  int id = blockIdx.x * 256 + threadIdx.x;
  if (id < B_*N_) {
    float4 v;
    v.x = xyz[id*3+0]; v.y = xyz[id*3+1]; v.z = xyz[id*3+2]; v.w = 0.f;
    xyzf[id] = v;
    return;
  }
  int wid = id - B_*N_;
  if (wid >= 2*WT_G) return;
  int g = wid / WT_G, r = wid % WT_G;
  float val;
  if (r < 4288) {                    // layer0: w (64,67) -> wt0[c*64+o]
    int c = r >> 6, o = r & 63;
    val = (g ? w10 : w00)[o*67 + c];
  } else if (r < 8384) {             // layer1: w (64,64) -> wt1[c*64+o]
    int rr = r - 4288; int c = rr >> 6, o = rr & 63;
    val = (g ? w11 : w01)[o*64 + c];
  } else if (r < 16576) {            // layer2: w (128,64) -> wt2[c*128+o]
    int rr = r - 8384; int c = rr >> 7, o = rr & 127;
    val = (g ? w12 : w02)[o*64 + c];
  } else {                           // biases: b0(64), b1(64), b2(128)
    int rr = r - 16576;
    val = (rr < 64)  ? (g ? b10 : b00)[rr]
        : (rr < 128) ? (g ? b11 : b01)[rr - 64]
                     : (g ? b12 : b02)[rr - 128];
  }
  wt[g*WT_G + r] = val;
}

// ---------------------------------------------------------------------------
// K1: furthest point sampling (bit-exact vs np: no-FMA f32, running min,
// argmax smallest-index tie-break). One block/batch.
// ---------------------------------------------------------------------------
__global__ __launch_bounds__(512) void fps_kernel(const float4* __restrict__ xyzf,
    float* __restrict__ nxyz, float* __restrict__ out_nxyz) {
  constexpr int PPT = 8;
  __shared__ float sx[N_*3];
  __shared__ float redv[8];
  __shared__ int   redi[8];
  __shared__ int   sel;
  const int b = blockIdx.x, t = threadIdx.x;
  const float4* xb = xyzf + b * N_;
  float px[PPT], py[PPT], pz[PPT], m[PPT];
#pragma unroll
  for (int p = 0; p < PPT; ++p) {
    int idx = t * PPT + p;
    float4 v = xb[idx];
    px[p] = v.x; py[p] = v.y; pz[p] = v.z; m[p] = 1e10f;
    sx[idx*3+0] = v.x; sx[idx*3+1] = v.y; sx[idx*3+2] = v.z;
  }
  if (t == 0) {
    float4 v = xb[0];
    int o = b * S_ * 3;
    nxyz[o] = v.x; nxyz[o+1] = v.y; nxyz[o+2] = v.z;
    out_nxyz[o] = v.x; out_nxyz[o+1] = v.y; out_nxyz[o+2] = v.z;
  }
  __syncthreads();
  int cur = 0;
  for (int i = 1; i < S_; ++i) {
    float lx = sx[cur*3], ly = sx[cur*3+1], lz = sx[cur*3+2];
    float bv = -1.f; int bi = 0;
#pragma unroll
    for (int p = 0; p < PPT; ++p) {
      float dx = __fsub_rn(px[p], lx), dy = __fsub_rn(py[p], ly), dz = __fsub_rn(pz[p], lz);
      float d = __fadd_rn(__fadd_rn(__fmul_rn(dx,dx), __fmul_rn(dy,dy)), __fmul_rn(dz,dz));
      m[p] = fminf(m[p], d);
      if (m[p] > bv) { bv = m[p]; bi = t * PPT + p; }
    }
#pragma unroll
    for (int off = 32; off >= 1; off >>= 1) {
      float ov = __shfl_down(bv, off);
      int   oi = __shfl_down(bi, off);
      if (ov > bv || (ov == bv && oi < bi)) { bv = ov; bi = oi; }
    }
    if ((t & 63) == 0) { redv[t >> 6] = bv; redi[t >> 6] = bi; }
    __syncthreads();
    if (t == 0) {
      float fv = redv[0]; int fi = redi[0];
#pragma unroll
      for (int w = 1; w < 8; ++w)
        if (redv[w] > fv || (redv[w] == fv && redi[w] < fi)) { fv = redv[w]; fi = redi[w]; }
      sel = fi;
      float nx = sx[fi*3], ny = sx[fi*3+1], nz = sx[fi*3+2];
      int o = (b * S_ + i) * 3;
      nxyz[o] = nx; nxyz[o+1] = ny; nxyz[o+2] = nz;
      out_nxyz[o] = nx; out_nxyz[o+1] = ny; out_nxyz[o+2] = nz;
    }
    __syncthreads();
    cur = sel;
  }
}

// ---------------------------------------------------------------------------
// K2: attention gate.
// ---------------------------------------------------------------------------
__global__ __launch_bounds__(256) void att_kernel(const float* __restrict__ nxyz,
    const float* __restrict__ w_att, const float* __restrict__ b_att,
    float* __restrict__ att) {
  __shared__ float ai[3 * S_];
  int b = blockIdx.x, t = threadIdx.x;
  for (int k = t; k < 3 * S_; k += 256) {
    int d = k >> 10, s = k & 1023;
    ai[k] = nxyz[(b * S_ + s) * 3 + d];
  }
  __syncthreads();
  float acc = b_att[t];
#pragma unroll 8
  for (int k = 0; k < 3 * S_; ++k)
    acc = fmaf(ai[k], w_att[k * 256 + t], acc);
  att[b * 256 + t] = 1.f / (1.f + expf(-acc));
}

// ---------------------------------------------------------------------------
// K3: ball query (bit-exact d2 < r2; first-NS in index order; pad first hit).
// ---------------------------------------------------------------------------
template<int NS>
__global__ __launch_bounds__(256) void ballq_kernel(const float4* __restrict__ xyzf,
    const float* __restrict__ nxyz, int* __restrict__ idxbuf, float r2) {
  int lane = threadIdx.x & 63;
  int cid = blockIdx.x * 4 + (threadIdx.x >> 6);
  int b = cid >> 10;
  float cx = nxyz[cid*3], cy = nxyz[cid*3+1], cz = nxyz[cid*3+2];
  const float4* xb = xyzf + b * N_;
  int cnt = 0, first = 0;
  for (int base = 0; base < N_; base += 64) {
    float4 P = xb[base + lane];
    float dx = __fsub_rn(cx, P.x), dy = __fsub_rn(cy, P.y), dz = __fsub_rn(cz, P.z);
    float d2 = __fadd_rn(__fadd_rn(__fmul_rn(dx,dx), __fmul_rn(dy,dy)), __fmul_rn(dz,dz));
    bool hit = d2 < r2;
    unsigned long long mask = __ballot(hit);
    if (cnt == 0 && mask != 0ull) first = base + (int)__builtin_ctzll(mask);
    if (hit) {
      int pos = cnt + (int)__popcll(mask & ((1ull << lane) - 1ull));
      if (pos < NS) idxbuf[cid * NS + pos] = base + lane;
    }
    cnt += (int)__popcll(mask);
    if (cnt >= NS) break;
  }
  if (cnt < NS)
    for (int p2 = cnt + lane; p2 < NS; p2 += 64) idxbuf[cid * NS + p2] = first;
}

// ---------------------------------------------------------------------------
// K4: GEMM-tiled fused group + MLP + maxpool + attention + store.
// 256 threads (4 waves), 128 columns/block (NCEN centers). Lane map:
// og = t&15 (out-group), cg = t>>4 (col-group of 8). Activations in one
// 67x132 LDS buffer, overwritten in place between layers (accs hold the full
// output tile). Weights read straight from L1 (contiguous 256 B per wave).
// ---------------------------------------------------------------------------
template<int NS>
__global__ __launch_bounds__(256, 4) void mlp_kernel(
    const float4* __restrict__ xyzf, const float* __restrict__ feats,
    const float* __restrict__ nxyz, const float* __restrict__ att,
    const int* __restrict__ idxbuf, const float* __restrict__ wt,
    float* __restrict__ outf, int g) {
  constexpr int NCEN = 128 / NS;   // centers per block (4 or 2)
  constexpr int XS = 132;          // padded LDS row stride (words)
  __shared__ float xs[67 * XS];    // 35.4 KB; rows 0..66 layer1, 0..63 after
  float* red = xs;                 // reused for maxpool combine
  const int t = threadIdx.x;
  const int cid0 = blockIdx.x * NCEN;
  const int b = cid0 >> 10;

  // ---- gather: 2 threads per column ----
  {
    const int col = t & 127, h = t >> 7;
    const int cidg = cid0 + col / NS;
    const int j = col % NS;
    const int p = idxbuf[cidg * NS + j];
    if (h == 0) {
      float4 P = xyzf[b * N_ + p];
      xs[0*XS+col] = __fsub_rn(P.x, nxyz[cidg*3+0]);
      xs[1*XS+col] = __fsub_rn(P.y, nxyz[cidg*3+1]);
      xs[2*XS+col] = __fsub_rn(P.z, nxyz[cidg*3+2]);
    }
    const float4* f4 = (const float4*)(feats + (size_t)(b*N_+p)*64) + h*8;
#pragma unroll
    for (int q = 0; q < 8; ++q) {
      float4 u = f4[q];
      int r = 3 + h*32 + q*4;
      xs[(r+0)*XS+col]=u.x; xs[(r+1)*XS+col]=u.y; xs[(r+2)*XS+col]=u.z; xs[(r+3)*XS+col]=u.w;
    }
  }
  __syncthreads();

  const int og = t & 15, cg = t >> 4;
  const float* w0  = wt;
  const float* w1  = wt + 67*64;
  const float* w2  = w1 + 64*64;
  const float* bb0 = w2 + 64*128;
  const float* bb1 = bb0 + 64;
  const float* bb2 = bb1 + 64;

  float acc[4][8];

  // ---- layer 1: 67 -> 64 ----
  {
    float4 bv = *(const float4*)&bb0[og*4];
    float b4[4] = {bv.x, bv.y, bv.z, bv.w};
#pragma unroll
    for (int oo = 0; oo < 4; ++oo)
#pragma unroll
      for (int cc = 0; cc < 8; ++cc) acc[oo][cc] = b4[oo];
    for (int k = 0; k < 67; ++k) {
      float4 x0 = *(const float4*)&xs[k*XS + cg*8];
      float4 x1 = *(const float4*)&xs[k*XS + cg*8 + 4];
      float4 wv = *(const float4*)&w0[k*64 + og*4];
      float x8[8] = {x0.x,x0.y,x0.z,x0.w,x1.x,x1.y,x1.z,x1.w};
      float w4[4] = {wv.x,wv.y,wv.z,wv.w};
#pragma unroll
      for (int oo = 0; oo < 4; ++oo)
#pragma unroll
        for (int cc = 0; cc < 8; ++cc) acc[oo][cc] = fmaf(w4[oo], x8[cc], acc[oo][cc]);
    }
  }
  __syncthreads();  // all xs reads done -> safe to overwrite
#pragma unroll
  for (int oo = 0; oo < 4; ++oo) {
    float4 y0, y1;
    y0.x=fmaxf(acc[oo][0],0.f); y0.y=fmaxf(acc[oo][1],0.f);
    y0.z=fmaxf(acc[oo][2],0.f); y0.w=fmaxf(acc[oo][3],0.f);
    y1.x=fmaxf(acc[oo][4],0.f); y1.y=fmaxf(acc[oo][5],0.f);
    y1.z=fmaxf(acc[oo][6],0.f); y1.w=fmaxf(acc[oo][7],0.f);
    *(float4*)&xs[(og*4+oo)*XS + cg*8]     = y0;
    *(float4*)&xs[(og*4+oo)*XS + cg*8 + 4] = y1;
  }
  __syncthreads();

  // ---- layer 2: 64 -> 64 ----
  {
    float4 bv = *(const float4*)&bb1[og*4];
    float b4[4] = {bv.x, bv.y, bv.z, bv.w};
#pragma unroll
    for (int oo = 0; oo < 4; ++oo)
#pragma unroll
      for (int cc = 0; cc < 8; ++cc) acc[oo][cc] = b4[oo];
    for (int k = 0; k < 64; ++k) {
      float4 x0 = *(const float4*)&xs[k*XS + cg*8];
      float4 x1 = *(const float4*)&xs[k*XS + cg*8 + 4];
      float4 wv = *(const float4*)&w1[k*64 + og*4];
      float x8[8] = {x0.x,x0.y,x0.z,x0.w,x1.x,x1.y,x1.z,x1.w};
      float w4[4] = {wv.x,wv.y,wv.z,wv.w};
#pragma unroll
      for (int oo = 0; oo < 4; ++oo)
#pragma unroll
        for (int cc = 0; cc < 8; ++cc) acc[oo][cc] = fmaf(w4[oo], x8[cc], acc[oo][cc]);
    }
  }
  __syncthreads();
#pragma unroll
  for (int oo = 0; oo < 4; ++oo) {
    float4 y0, y1;
    y0.x=fmaxf(acc[oo][0],0.f); y0.y=fmaxf(acc[oo][1],0.f);
    y0.z=fmaxf(acc[oo][2],0.f); y0.w=fmaxf(acc[oo][3],0.f);
    y1.x=fmaxf(acc[oo][4],0.f); y1.y=fmaxf(acc[oo][5],0.f);
    y1.z=fmaxf(acc[oo][6],0.f); y1.w=fmaxf(acc[oo][7],0.f);
    *(float4*)&xs[(og*4+oo)*XS + cg*8]     = y0;
    *(float4*)&xs[(og*4+oo)*XS + cg*8 + 4] = y1;
  }
  __syncthreads();

  // ---- layer 3: 64 -> 128, ReLU + in-register partial maxpool ----
  float acc3[8][8];
  {
    float4 b0v = *(const float4*)&bb2[og*8];
    float4 b1v = *(const float4*)&bb2[og*8 + 4];
    float b8[8] = {b0v.x,b0v.y,b0v.z,b0v.w,b1v.x,b1v.y,b1v.z,b1v.w};
#pragma unroll
    for (int oo = 0; oo < 8; ++oo)
#pragma unroll
      for (int cc = 0; cc < 8; ++cc) acc3[oo][cc] = b8[oo];
    for (int k = 0; k < 64; ++k) {
      float4 x0 = *(const float4*)&xs[k*XS + cg*8];
      float4 x1 = *(const float4*)&xs[k*XS + cg*8 + 4];
      float4 wa = *(const float4*)&w2[k*128 + og*8];
      float4 wb = *(const float4*)&w2[k*128 + og*8 + 4];
      float x8[8] = {x0.x,x0.y,x0.z,x0.w,x1.x,x1.y,x1.z,x1.w};
      float w8[8] = {wa.x,wa.y,wa.z,wa.w,wb.x,wb.y,wb.z,wb.w};
#pragma unroll
      for (int oo = 0; oo < 8; ++oo)
#pragma unroll
        for (int cc = 0; cc < 8; ++cc) acc3[oo][cc] = fmaf(w8[oo], x8[cc], acc3[oo][cc]);
    }
  }
  // per-thread max over its 8 columns
  float pm[8];
#pragma unroll
  for (int oo = 0; oo < 8; ++oo) {
    float v = fmaxf(acc3[oo][0], 0.f);
#pragma unroll
    for (int cc = 1; cc < 8; ++cc) v = fmaxf(v, fmaxf(acc3[oo][cc], 0.f));
    pm[oo] = v;
  }
  // wave-level max across the 4 col-groups (lane bits 4,5); wave w owns
  // columns w*32..w*32+31.
#pragma unroll
  for (int oo = 0; oo < 8; ++oo) {
    pm[oo] = fmaxf(pm[oo], __shfl_xor(pm[oo], 16));
    pm[oo] = fmaxf(pm[oo], __shfl_xor(pm[oo], 32));
  }
  __syncthreads();  // all xs reads done -> reuse as red
  if ((t & 63) < 16) {
    int w = t >> 6;
#pragma unroll
    for (int oo = 0; oo < 8; ++oo) red[w*128 + og*8 + oo] = pm[oo];
  }
  __syncthreads();

  // ---- combine (NS=64: pairs of waves), attention scale, store ----
  const int ch = t & 127;
  const float a = att[b*256 + g*128 + ch];
  if (NS == 64) {
    int c = t >> 7;                       // 0..1
    float v = fmaxf(red[(2*c)*128 + ch], red[(2*c+1)*128 + ch]);
    int s = (cid0 + c) & 1023;
    outf[((size_t)(b*256 + g*128 + ch)) * 1024 + s] = v * a;
  } else {
#pragma unroll
    for (int kk = 0; kk < 2; ++kk) {
      int c = (t >> 7) * 2 + kk;          // 0..3
      float v = red[c*128 + ch];
      int s = (cid0 + c) & 1023;
      outf[((size_t)(b*256 + g*128 + ch)) * 1024 + s] = v * a;
    }
  }
}

// ---------------------------------------------------------------------------
extern "C" void kernel_launch(void* const* d_in, const int* in_sizes, int n_in,
                              void* d_out, int out_size, void* d_ws, size_t ws_size,
                              hipStream_t stream) {
  const float* xyz   = (const float*)d_in[0];
  const float* feats = (const float*)d_in[1];
  const float* w_att = (const float*)d_in[2];
  const float* b_att = (const float*)d_in[3];
  const float* w00 = (const float*)d_in[4];
  const float* b00 = (const float*)d_in[5];
  const float* w01 = (const float*)d_in[6];
  const float* b01 = (const float*)d_in[7];
  const float* w02 = (const float*)d_in[8];
  const float* b02 = (const float*)d_in[9];
  const float* w10 = (const float*)d_in[10];
  const float* b10 = (const float*)d_in[11];
  const float* w11 = (const float*)d_in[12];
  const float* b11 = (const float*)d_in[13];
  const float* w12 = (const float*)d_in[14];
  const float* b12 = (const float*)d_in[15];

  float* wsf = (float*)d_ws;
  int*   wsi = (int*)d_ws;
  float4* xyzf = (float4*)(wsf + WS_XYZF);
  float* nxyz  = wsf + WS_NXYZ;
  float* att   = wsf + WS_ATT;
  float* wt    = wsf + WS_WT;
  int* idx0 = wsi + WS_IDX0;
  int* idx1 = wsi + WS_IDX1;

  float* out  = (float*)d_out;
  float* outf = out + B_ * S_ * 3;

  int cvt_total = B_*N_ + 2*WT_G;
  hipLaunchKernelGGL(convert_kernel, dim3((cvt_total + 255) / 256), dim3(256), 0, stream,
                     xyz, w00, w01, w02, b00, b01, b02, w10, w11, w12, b10, b11, b12,
                     xyzf, wt);
  hipLaunchKernelGGL(fps_kernel, dim3(B_), dim3(512), 0, stream, xyzf, nxyz, out);
  hipLaunchKernelGGL(att_kernel, dim3(B_), dim3(256), 0, stream, nxyz, w_att, b_att, att);
  hipLaunchKernelGGL((ballq_kernel<32>), dim3(B_*S_/4), dim3(256), 0, stream,
                     xyzf, nxyz, idx0, (float)(0.2 * 0.2));
  hipLaunchKernelGGL((ballq_kernel<64>), dim3(B_*S_/4), dim3(256), 0, stream,
                     xyzf, nxyz, idx1, (float)(0.4 * 0.4));
  hipLaunchKernelGGL((mlp_kernel<32>), dim3(B_*S_*32/128), dim3(256), 0, stream,
                     xyzf, feats, nxyz, att, idx0, wt, outf, 0);
  hipLaunchKernelGGL((mlp_kernel<64>), dim3(B_*S_*64/128), dim3(256), 0, stream,
                     xyzf, feats, nxyz, att, idx1, wt + WT_G, outf, 1);
}

// Round 5
// 2224.026 us; speedup vs baseline: 8.5409x; 1.1023x over previous
//
#include <hip/hip_runtime.h>
#include <cstdint>
#include <cstddef>

// ---------------------------------------------------------------------------
// PointNet++ SA module (multi-scale grouping) with attention gate.
// B=16, N=4096, C_IN=64, NPOINT=1024, radii (0.2,0.4), nsamples (32,64),
// MLPs ((64,64,128),(64,64,128)), C_TOTAL=256. Inputs f32, output f32.
// Round 5: FPS loop restructured to 1 barrier/iter, no global stores in loop,
// all-thread redundant argmax combine (double-buffered LDS). Ball queries
// fused into one kernel. MLP kernels unchanged from round 4 (GEMM-tiled).
// ---------------------------------------------------------------------------

constexpr int B_ = 16, N_ = 4096, S_ = 1024;
constexpr int WT_G = 67*64 + 64*64 + 128*64 + 64 + 64 + 128; // 16832 floats/group

// workspace layout in 4-byte units
constexpr int WS_XYZF = 0;                       // float4[B*N]
constexpr int WS_NXYZ = B_*N_*4;                 // float[B*S*3]
constexpr int WS_ATT  = WS_NXYZ + B_*S_*3;       // float[B*256]
constexpr int WS_WT   = WS_ATT + B_*256;         // float[2*WT_G]
constexpr int WS_IDX0 = WS_WT + 2*WT_G;          // int[B*S*32]
constexpr int WS_IDX1 = WS_IDX0 + B_*S_*32;      // int[B*S*64]

// ---------------------------------------------------------------------------
// K0: xyz -> float4 padding; weights transposed to [cin][cout].
// ---------------------------------------------------------------------------
__global__ __launch_bounds__(256) void convert_kernel(
    const float* __restrict__ xyz,
    const float* __restrict__ w00, const float* __restrict__ w01,
    const float* __restrict__ w02, const float* __restrict__ b00,
    const float* __restrict__ b01, const float* __restrict__ b02,
    const float* __restrict__ w10, const float* __restrict__ w11,
    const float* __restrict__ w12, const float* __restrict__ b10,
    const float* __restrict__ b11, const float* __restrict__ b12,
    float4* __restrict__ xyzf, float* __restrict__ wt) {
  int id = blockIdx.x * 256 + threadIdx.x;
  if (id < B_*N_) {
    float4 v;
    v.x = xyz[id*3+0]; v.y = xyz[id*3+1]; v.z = xyz[id*3+2]; v.w = 0.f;
    xyzf[id] = v;
    return;
  }
  int wid = id - B_*N_;
  if (wid >= 2*WT_G) return;
  int g = wid / WT_G, r = wid % WT_G;
  float val;
  if (r < 4288) {                    // layer0: w (64,67) -> wt0[c*64+o]
    int c = r >> 6, o = r & 63;
    val = (g ? w10 : w00)[o*67 + c];
  } else if (r < 8384) {             // layer1: w (64,64) -> wt1[c*64+o]
    int rr = r - 4288; int c = rr >> 6, o = rr & 63;
    val = (g ? w11 : w01)[o*64 + c];
  } else if (r < 16576) {            // layer2: w (128,64) -> wt2[c*128+o]
    int rr = r - 8384; int c = rr >> 7, o = rr & 127;
    val = (g ? w12 : w02)[o*64 + c];
  } else {                           // biases
    int rr = r - 16576;
    val = (rr < 64)  ? (g ? b10 : b00)[rr]
        : (rr < 128) ? (g ? b11 : b01)[rr - 64]
                     : (g ? b12 : b02)[rr - 128];
  }
  wt[g*WT_G + r] = val;
}

// ---------------------------------------------------------------------------
// K1: furthest point sampling, 1 barrier per iteration.
// Bit-exact vs np: no-FMA f32 distances, running min, argmax with
// smallest-index tie-break (lexicographic (value,-index) order, associative).
// No global stores inside the loop (selidx buffered in LDS; coalesced
// epilogue). Double-buffered redv/redi: wave drift bounded by the single
// barrier, so parity ping-pong is race-free.
// ---------------------------------------------------------------------------
__global__ __launch_bounds__(512) void fps_kernel(const float4* __restrict__ xyzf,
    float* __restrict__ nxyz, float* __restrict__ out_nxyz) {
  constexpr int PPT = 8;
  __shared__ float sx[N_*3];
  __shared__ int   selidx[S_];
  __shared__ alignas(16) float redv[2][8];
  __shared__ alignas(16) int   redi[2][8];
  const int b = blockIdx.x, t = threadIdx.x;
  const float4* xb = xyzf + b * N_;
  float px[PPT], py[PPT], pz[PPT], m[PPT];
#pragma unroll
  for (int p = 0; p < PPT; ++p) {
    int idx = t * PPT + p;
    float4 v = xb[idx];
    px[p] = v.x; py[p] = v.y; pz[p] = v.z; m[p] = 1e10f;
    sx[idx*3+0] = v.x; sx[idx*3+1] = v.y; sx[idx*3+2] = v.z;
  }
  if (t == 0) selidx[0] = 0;   // first sampled index is 0 (matches reference)
  __syncthreads();
  int cur = 0;
  for (int i = 1; i < S_; ++i) {
    float lx = sx[cur*3], ly = sx[cur*3+1], lz = sx[cur*3+2];
    float bv = -1.f; int bi = 0;
#pragma unroll
    for (int p = 0; p < PPT; ++p) {
      float dx = __fsub_rn(px[p], lx), dy = __fsub_rn(py[p], ly), dz = __fsub_rn(pz[p], lz);
      float d = __fadd_rn(__fadd_rn(__fmul_rn(dx,dx), __fmul_rn(dy,dy)), __fmul_rn(dz,dz));
      m[p] = fminf(m[p], d);
      if (m[p] > bv) { bv = m[p]; bi = t * PPT + p; }   // strict > keeps smallest idx
    }
#pragma unroll
    for (int off = 1; off < 64; off <<= 1) {
      float ov = __shfl_xor(bv, off);
      int   oi = __shfl_xor(bi, off);
      if (ov > bv || (ov == bv && oi < bi)) { bv = ov; bi = oi; }
    }
    const int par = i & 1;
    if ((t & 63) == 0) { redv[par][t >> 6] = bv; redi[par][t >> 6] = bi; }
    __syncthreads();
    // every thread combines the 8 wave results (broadcast LDS reads)
    float4 va = *(const float4*)&redv[par][0];
    float4 vb = *(const float4*)&redv[par][4];
    int4   ia = *(const int4*)&redi[par][0];
    int4   ib = *(const int4*)&redi[par][4];
    float fv = va.x; int fi = ia.x;
#define CMB(v, ix) if ((v) > fv || ((v) == fv && (ix) < fi)) { fv = (v); fi = (ix); }
    CMB(va.y, ia.y) CMB(va.z, ia.z) CMB(va.w, ia.w)
    CMB(vb.x, ib.x) CMB(vb.y, ib.y) CMB(vb.z, ib.z) CMB(vb.w, ib.w)
#undef CMB
    cur = fi;
    if (t == 0) selidx[i] = fi;
  }
  __syncthreads();
  // epilogue: coalesced write of new_xyz to workspace + output
  for (int k = t; k < S_; k += 512) {
    int id = selidx[k];
    float x = sx[id*3], y = sx[id*3+1], z = sx[id*3+2];
    int o = (b * S_ + k) * 3;
    nxyz[o] = x; nxyz[o+1] = y; nxyz[o+2] = z;
    out_nxyz[o] = x; out_nxyz[o+1] = y; out_nxyz[o+2] = z;
  }
}

// ---------------------------------------------------------------------------
// K2: attention gate.
// ---------------------------------------------------------------------------
__global__ __launch_bounds__(256) void att_kernel(const float* __restrict__ nxyz,
    const float* __restrict__ w_att, const float* __restrict__ b_att,
    float* __restrict__ att) {
  __shared__ float ai[3 * S_];
  int b = blockIdx.x, t = threadIdx.x;
  for (int k = t; k < 3 * S_; k += 256) {
    int d = k >> 10, s = k & 1023;
    ai[k] = nxyz[(b * S_ + s) * 3 + d];
  }
  __syncthreads();
  float acc = b_att[t];
#pragma unroll 8
  for (int k = 0; k < 3 * S_; ++k)
    acc = fmaf(ai[k], w_att[k * 256 + t], acc);
  att[b * 256 + t] = 1.f / (1.f + expf(-acc));
}

// ---------------------------------------------------------------------------
// K3: fused dual-radius ball query. One wave per center; one distance
// computation serves both radii (hit0 ⊆ hit1). Bit-exact d2 < r2 in
// non-contracted f32; first-NS in ascending index order; pad with first hit
// (center itself always hits, d2 = 0).
// ---------------------------------------------------------------------------
__global__ __launch_bounds__(256) void ballq2_kernel(const float4* __restrict__ xyzf,
    const float* __restrict__ nxyz, int* __restrict__ idx0buf, int* __restrict__ idx1buf) {
  const float r2a = (float)(0.2 * 0.2), r2b = (float)(0.4 * 0.4);
  int lane = threadIdx.x & 63;
  int cid = blockIdx.x * 4 + (threadIdx.x >> 6);
  int b = cid >> 10;
  float cx = nxyz[cid*3], cy = nxyz[cid*3+1], cz = nxyz[cid*3+2];
  const float4* xb = xyzf + b * N_;
  int cnt0 = 0, cnt1 = 0, first0 = 0, first1 = 0;
  const unsigned long long below = (1ull << lane) - 1ull;
  for (int base = 0; base < N_; base += 64) {
    float4 P = xb[base + lane];
    float dx = __fsub_rn(cx, P.x), dy = __fsub_rn(cy, P.y), dz = __fsub_rn(cz, P.z);
    float d2 = __fadd_rn(__fadd_rn(__fmul_rn(dx,dx), __fmul_rn(dy,dy)), __fmul_rn(dz,dz));
    bool h0 = d2 < r2a, h1 = d2 < r2b;
    unsigned long long m0 = __ballot(h0), m1 = __ballot(h1);
    if (cnt0 == 0 && m0 != 0ull) first0 = base + (int)__builtin_ctzll(m0);
    if (cnt1 == 0 && m1 != 0ull) first1 = base + (int)__builtin_ctzll(m1);
    if (h0) {
      int pos = cnt0 + (int)__popcll(m0 & below);
      if (pos < 32) idx0buf[cid * 32 + pos] = base + lane;
    }
    if (h1) {
      int pos = cnt1 + (int)__popcll(m1 & below);
      if (pos < 64) idx1buf[cid * 64 + pos] = base + lane;
    }
    cnt0 += (int)__popcll(m0);
    cnt1 += (int)__popcll(m1);
    if (cnt0 >= 32 && cnt1 >= 64) break;
  }
  if (cnt0 < 32)
    for (int p = cnt0 + lane; p < 32; p += 64) idx0buf[cid * 32 + p] = first0;
  if (cnt1 < 64)
    for (int p = cnt1 + lane; p < 64; p += 64) idx1buf[cid * 64 + p] = first1;
}

// ---------------------------------------------------------------------------
// K4: GEMM-tiled fused group + MLP + maxpool + attention + store (round 4).
// 256 threads (4 waves), 128 columns/block. og = t&15, cg = t>>4.
// ---------------------------------------------------------------------------
template<int NS>
__global__ __launch_bounds__(256, 4) void mlp_kernel(
    const float4* __restrict__ xyzf, const float* __restrict__ feats,
    const float* __restrict__ nxyz, const float* __restrict__ att,
    const int* __restrict__ idxbuf, const float* __restrict__ wt,
    float* __restrict__ outf, int g) {
  constexpr int NCEN = 128 / NS;
  constexpr int XS = 132;
  __shared__ float xs[67 * XS];
  float* red = xs;
  const int t = threadIdx.x;
  const int cid0 = blockIdx.x * NCEN;
  const int b = cid0 >> 10;

  {
    const int col = t & 127, h = t >> 7;
    const int cidg = cid0 + col / NS;
    const int j = col % NS;
    const int p = idxbuf[cidg * NS + j];
    if (h == 0) {
      float4 P = xyzf[b * N_ + p];
      xs[0*XS+col] = __fsub_rn(P.x, nxyz[cidg*3+0]);
      xs[1*XS+col] = __fsub_rn(P.y, nxyz[cidg*3+1]);
      xs[2*XS+col] = __fsub_rn(P.z, nxyz[cidg*3+2]);
    }
    const float4* f4 = (const float4*)(feats + (size_t)(b*N_+p)*64) + h*8;
#pragma unroll
    for (int q = 0; q < 8; ++q) {
      float4 u = f4[q];
      int r = 3 + h*32 + q*4;
      xs[(r+0)*XS+col]=u.x; xs[(r+1)*XS+col]=u.y; xs[(r+2)*XS+col]=u.z; xs[(r+3)*XS+col]=u.w;
    }
  }
  __syncthreads();

  const int og = t & 15, cg = t >> 4;
  const float* w0  = wt;
  const float* w1  = wt + 67*64;
  const float* w2  = w1 + 64*64;
  const float* bb0 = w2 + 64*128;
  const float* bb1 = bb0 + 64;
  const float* bb2 = bb1 + 64;

  float acc[4][8];

  // ---- layer 1: 67 -> 64 ----
  {
    float4 bv = *(const float4*)&bb0[og*4];
    float b4[4] = {bv.x, bv.y, bv.z, bv.w};
#pragma unroll
    for (int oo = 0; oo < 4; ++oo)
#pragma unroll
      for (int cc = 0; cc < 8; ++cc) acc[oo][cc] = b4[oo];
    for (int k = 0; k < 67; ++k) {
      float4 x0 = *(const float4*)&xs[k*XS + cg*8];
      float4 x1 = *(const float4*)&xs[k*XS + cg*8 + 4];
      float4 wv = *(const float4*)&w0[k*64 + og*4];
      float x8[8] = {x0.x,x0.y,x0.z,x0.w,x1.x,x1.y,x1.z,x1.w};
      float w4[4] = {wv.x,wv.y,wv.z,wv.w};
#pragma unroll
      for (int oo = 0; oo < 4; ++oo)
#pragma unroll
        for (int cc = 0; cc < 8; ++cc) acc[oo][cc] = fmaf(w4[oo], x8[cc], acc[oo][cc]);
    }
  }
  __syncthreads();
#pragma unroll
  for (int oo = 0; oo < 4; ++oo) {
    float4 y0, y1;
    y0.x=fmaxf(acc[oo][0],0.f); y0.y=fmaxf(acc[oo][1],0.f);
    y0.z=fmaxf(acc[oo][2],0.f); y0.w=fmaxf(acc[oo][3],0.f);
    y1.x=fmaxf(acc[oo][4],0.f); y1.y=fmaxf(acc[oo][5],0.f);
    y1.z=fmaxf(acc[oo][6],0.f); y1.w=fmaxf(acc[oo][7],0.f);
    *(float4*)&xs[(og*4+oo)*XS + cg*8]     = y0;
    *(float4*)&xs[(og*4+oo)*XS + cg*8 + 4] = y1;
  }
  __syncthreads();

  // ---- layer 2: 64 -> 64 ----
  {
    float4 bv = *(const float4*)&bb1[og*4];
    float b4[4] = {bv.x, bv.y, bv.z, bv.w};
#pragma unroll
    for (int oo = 0; oo < 4; ++oo)
#pragma unroll
      for (int cc = 0; cc < 8; ++cc) acc[oo][cc] = b4[oo];
    for (int k = 0; k < 64; ++k) {
      float4 x0 = *(const float4*)&xs[k*XS + cg*8];
      float4 x1 = *(const float4*)&xs[k*XS + cg*8 + 4];
      float4 wv = *(const float4*)&w1[k*64 + og*4];
      float x8[8] = {x0.x,x0.y,x0.z,x0.w,x1.x,x1.y,x1.z,x1.w};
      float w4[4] = {wv.x,wv.y,wv.z,wv.w};
#pragma unroll
      for (int oo = 0; oo < 4; ++oo)
#pragma unroll
        for (int cc = 0; cc < 8; ++cc) acc[oo][cc] = fmaf(w4[oo], x8[cc], acc[oo][cc]);
    }
  }
  __syncthreads();
#pragma unroll
  for (int oo = 0; oo < 4; ++oo) {
    float4 y0, y1;
    y0.x=fmaxf(acc[oo][0],0.f); y0.y=fmaxf(acc[oo][1],0.f);
    y0.z=fmaxf(acc[oo][2],0.f); y0.w=fmaxf(acc[oo][3],0.f);
    y1.x=fmaxf(acc[oo][4],0.f); y1.y=fmaxf(acc[oo][5],0.f);
    y1.z=fmaxf(acc[oo][6],0.f); y1.w=fmaxf(acc[oo][7],0.f);
    *(float4*)&xs[(og*4+oo)*XS + cg*8]     = y0;
    *(float4*)&xs[(og*4+oo)*XS + cg*8 + 4] = y1;
  }
  __syncthreads();

  // ---- layer 3: 64 -> 128, ReLU + in-register partial maxpool ----
  float acc3[8][8];
  {
    float4 b0v = *(const float4*)&bb2[og*8];
    float4 b1v = *(const float4*)&bb2[og*8 + 4];
    float b8[8] = {b0v.x,b0v.y,b0v.z,b0v.w,b1v.x,b1v.y,b1v.z,b1v.w};
#pragma unroll
    for (int oo = 0; oo < 8; ++oo)
#pragma unroll
      for (int cc = 0; cc < 8; ++cc) acc3[oo][cc] = b8[oo];
    for (int k = 0; k < 64; ++k) {
      float4 x0 = *(const float4*)&xs[k*XS + cg*8];
      float4 x1 = *(const float4*)&xs[k*XS + cg*8 + 4];
      float4 wa = *(const float4*)&w2[k*128 + og*8];
      float4 wb = *(const float4*)&w2[k*128 + og*8 + 4];
      float x8[8] = {x0.x,x0.y,x0.z,x0.w,x1.x,x1.y,x1.z,x1.w};
      float w8[8] = {wa.x,wa.y,wa.z,wa.w,wb.x,wb.y,wb.z,wb.w};
#pragma unroll
      for (int oo = 0; oo < 8; ++oo)
#pragma unroll
        for (int cc = 0; cc < 8; ++cc) acc3[oo][cc] = fmaf(w8[oo], x8[cc], acc3[oo][cc]);
    }
  }
  float pm[8];
#pragma unroll
  for (int oo = 0; oo < 8; ++oo) {
    float v = fmaxf(acc3[oo][0], 0.f);
#pragma unroll
    for (int cc = 1; cc < 8; ++cc) v = fmaxf(v, fmaxf(acc3[oo][cc], 0.f));
    pm[oo] = v;
  }
#pragma unroll
  for (int oo = 0; oo < 8; ++oo) {
    pm[oo] = fmaxf(pm[oo], __shfl_xor(pm[oo], 16));
    pm[oo] = fmaxf(pm[oo], __shfl_xor(pm[oo], 32));
  }
  __syncthreads();
  if ((t & 63) < 16) {
    int w = t >> 6;
#pragma unroll
    for (int oo = 0; oo < 8; ++oo) red[w*128 + og*8 + oo] = pm[oo];
  }
  __syncthreads();

  const int ch = t & 127;
  const float a = att[b*256 + g*128 + ch];
  if (NS == 64) {
    int c = t >> 7;
    float v = fmaxf(red[(2*c)*128 + ch], red[(2*c+1)*128 + ch]);
    int s = (cid0 + c) & 1023;
    outf[((size_t)(b*256 + g*128 + ch)) * 1024 + s] = v * a;
  } else {
#pragma unroll
    for (int kk = 0; kk < 2; ++kk) {
      int c = (t >> 7) * 2 + kk;
      float v = red[c*128 + ch];
      int s = (cid0 + c) & 1023;
      outf[((size_t)(b*256 + g*128 + ch)) * 1024 + s] = v * a;
    }
  }
}

// ---------------------------------------------------------------------------
extern "C" void kernel_launch(void* const* d_in, const int* in_sizes, int n_in,
                              void* d_out, int out_size, void* d_ws, size_t ws_size,
                              hipStream_t stream) {
  const float* xyz   = (const float*)d_in[0];
  const float* feats = (const float*)d_in[1];
  const float* w_att = (const float*)d_in[2];
  const float* b_att = (const float*)d_in[3];
  const float* w00 = (const float*)d_in[4];
  const float* b00 = (const float*)d_in[5];
  const float* w01 = (const float*)d_in[6];
  const float* b01 = (const float*)d_in[7];
  const float* w02 = (const float*)d_in[8];
  const float* b02 = (const float*)d_in[9];
  const float* w10 = (const float*)d_in[10];
  const float* b10 = (const float*)d_in[11];
  const float* w11 = (const float*)d_in[12];
  const float* b11 = (const float*)d_in[13];
  const float* w12 = (const float*)d_in[14];
  const float* b12 = (const float*)d_in[15];

  float* wsf = (float*)d_ws;
  int*   wsi = (int*)d_ws;
  float4* xyzf = (float4*)(wsf + WS_XYZF);
  float* nxyz  = wsf + WS_NXYZ;
  float* att   = wsf + WS_ATT;
  float* wt    = wsf + WS_WT;
  int* idx0 = wsi + WS_IDX0;
  int* idx1 = wsi + WS_IDX1;

  float* out  = (float*)d_out;
  float* outf = out + B_ * S_ * 3;

  int cvt_total = B_*N_ + 2*WT_G;
  hipLaunchKernelGGL(convert_kernel, dim3((cvt_total + 255) / 256), dim3(256), 0, stream,
                     xyz, w00, w01, w02, b00, b01, b02, w10, w11, w12, b10, b11, b12,
                     xyzf, wt);
  hipLaunchKernelGGL(fps_kernel, dim3(B_), dim3(512), 0, stream, xyzf, nxyz, out);
  hipLaunchKernelGGL(att_kernel, dim3(B_), dim3(256), 0, stream, nxyz, w_att, b_att, att);
  hipLaunchKernelGGL(ballq2_kernel, dim3(B_*S_/4), dim3(256), 0, stream,
                     xyzf, nxyz, idx0, idx1);
  hipLaunchKernelGGL((mlp_kernel<32>), dim3(B_*S_*32/128), dim3(256), 0, stream,
                     xyzf, feats, nxyz, att, idx0, wt, outf, 0);
  hipLaunchKernelGGL((mlp_kernel<64>), dim3(B_*S_*64/128), dim3(256), 0, stream,
                     xyzf, feats, nxyz, att, idx1, wt + WT_G, outf, 1);
}

// Round 6
// 1855.219 us; speedup vs baseline: 10.2388x; 1.1988x over previous
//
#include <hip/hip_runtime.h>
#include <cstdint>
#include <cstddef>

// ---------------------------------------------------------------------------
// PointNet++ SA module (multi-scale grouping) with attention gate.
// B=16, N=4096, C_IN=64, NPOINT=1024, radii (0.2,0.4), nsamples (32,64),
// MLPs ((64,64,128),(64,64,128)), C_TOTAL=256. Inputs f32, output f32.
// Round 6: FPS inner loop rebuilt around DPP wave-max + ballot index pick +
// speculative coordinate forwarding (no ds_swizzle shuffles, 1 barrier/iter,
// no dependent LDS broadcast read). Everything else unchanged from round 5.
// ---------------------------------------------------------------------------

constexpr int B_ = 16, N_ = 4096, S_ = 1024;
constexpr int WT_G = 67*64 + 64*64 + 128*64 + 64 + 64 + 128; // 16832 floats/group

// workspace layout in 4-byte units
constexpr int WS_XYZF = 0;                       // float4[B*N]
constexpr int WS_NXYZ = B_*N_*4;                 // float[B*S*3]
constexpr int WS_ATT  = WS_NXYZ + B_*S_*3;       // float[B*256]
constexpr int WS_WT   = WS_ATT + B_*256;         // float[2*WT_G]
constexpr int WS_IDX0 = WS_WT + 2*WT_G;          // int[B*S*32]
constexpr int WS_IDX1 = WS_IDX0 + B_*S_*32;      // int[B*S*64]

// ---------------------------------------------------------------------------
// K0: xyz -> float4 padding; weights transposed to [cin][cout].
// ---------------------------------------------------------------------------
__global__ __launch_bounds__(256) void convert_kernel(
    const float* __restrict__ xyz,
    const float* __restrict__ w00, const float* __restrict__ w01,
    const float* __restrict__ w02, const float* __restrict__ b00,
    const float* __restrict__ b01, const float* __restrict__ b02,
    const float* __restrict__ w10, const float* __restrict__ w11,
    const float* __restrict__ w12, const float* __restrict__ b10,
    const float* __restrict__ b11, const float* __restrict__ b12,
    float4* __restrict__ xyzf, float* __restrict__ wt) {
  int id = blockIdx.x * 256 + threadIdx.x;
  if (id < B_*N_) {
    float4 v;
    v.x = xyz[id*3+0]; v.y = xyz[id*3+1]; v.z = xyz[id*3+2]; v.w = 0.f;
    xyzf[id] = v;
    return;
  }
  int wid = id - B_*N_;
  if (wid >= 2*WT_G) return;
  int g = wid / WT_G, r = wid % WT_G;
  float val;
  if (r < 4288) {                    // layer0: w (64,67) -> wt0[c*64+o]
    int c = r >> 6, o = r & 63;
    val = (g ? w10 : w00)[o*67 + c];
  } else if (r < 8384) {             // layer1: w (64,64) -> wt1[c*64+o]
    int rr = r - 4288; int c = rr >> 6, o = rr & 63;
    val = (g ? w11 : w01)[o*64 + c];
  } else if (r < 16576) {            // layer2: w (128,64) -> wt2[c*128+o]
    int rr = r - 8384; int c = rr >> 7, o = rr & 127;
    val = (g ? w12 : w02)[o*64 + c];
  } else {                           // biases
    int rr = r - 16576;
    val = (rr < 64)  ? (g ? b10 : b00)[rr]
        : (rr < 128) ? (g ? b11 : b01)[rr - 64]
                     : (g ? b12 : b02)[rr - 128];
  }
  wt[g*WT_G + r] = val;
}

// ---------------------------------------------------------------------------
// K1: furthest point sampling. One block/batch, 512 thr x 8 pts in registers.
// Per iteration: no-FMA f32 distance update (bit-exact vs np), local strict->
// argmax, DPP wave max (uint domain, all m>=0), ballot+ctz+readlane for the
// smallest index attaining it, winner lane forwards coords + packed
// (val, ~idx) key to double-buffered LDS, ONE barrier, all threads combine 8
// keys with a u64-max tree (lexicographic, associative => np-exact) and pick
// the coords via cndmask tree. selidx buffered in LDS; coalesced epilogue.
// ---------------------------------------------------------------------------
__global__ __launch_bounds__(512) void fps_kernel(const float4* __restrict__ xyzf,
    float* __restrict__ nxyz, float* __restrict__ out_nxyz) {
  constexpr int PPT = 8;
  __shared__ float sx[N_*3];
  __shared__ int   selidx[S_];
  __shared__ alignas(16) unsigned long long redP[2][8];
  __shared__ alignas(16) float4 redC[2][8];
  const int b = blockIdx.x, t = threadIdx.x;
  const int wv = t >> 6;  // wave id 0..7
  const float4* xb = xyzf + b * N_;
  float px[PPT], py[PPT], pz[PPT], m[PPT];
#pragma unroll
  for (int p = 0; p < PPT; ++p) {
    int idx = t * PPT + p;
    float4 v = xb[idx];
    px[p] = v.x; py[p] = v.y; pz[p] = v.z; m[p] = 1e10f;
    sx[idx*3+0] = v.x; sx[idx*3+1] = v.y; sx[idx*3+2] = v.z;
  }
  if (t == 0) selidx[0] = 0;   // first sampled index is 0 (matches reference)
  __syncthreads();
  float lx = sx[0], ly = sx[1], lz = sx[2];
  for (int i = 1; i < S_; ++i) {
    // ---- distance update + local argmax (strict > keeps smallest idx) ----
    float bv = -1.f; int bp = 0;
#pragma unroll
    for (int p = 0; p < PPT; ++p) {
      float dx = __fsub_rn(px[p], lx), dy = __fsub_rn(py[p], ly), dz = __fsub_rn(pz[p], lz);
      float d = __fadd_rn(__fadd_rn(__fmul_rn(dx,dx), __fmul_rn(dy,dy)), __fmul_rn(dz,dz));
      m[p] = fminf(m[p], d);
      if (m[p] > bv) { bv = m[p]; bp = p; }
    }
    const int bi = t * PPT + bp;
    // ---- wave max via DPP (uint compare valid: all m >= 0, no NaN) ----
    unsigned vm = __float_as_uint(bv);
#define DPP_MAX(ctrl) { unsigned o = (unsigned)__builtin_amdgcn_update_dpp((int)vm, (int)vm, (ctrl), 0xf, 0xf, false); vm = vm > o ? vm : o; }
    DPP_MAX(0x111)  // row_shr:1
    DPP_MAX(0x112)  // row_shr:2
    DPP_MAX(0x114)  // row_shr:4
    DPP_MAX(0x118)  // row_shr:8
    DPP_MAX(0x142)  // row_bcast:15
    DPP_MAX(0x143)  // row_bcast:31
#undef DPP_MAX
    const unsigned wmaxu = (unsigned)__builtin_amdgcn_readlane((int)vm, 63);
    // smallest index attaining the wave max: lanes are index-ordered
    const unsigned long long mk = __ballot(__float_as_uint(bv) == wmaxu);
    const int fl = (int)__builtin_ctzll(mk);
    const int widx = __builtin_amdgcn_readlane(bi, fl);
    const int par = i & 1;
    // ---- winner lane forwards packed key + its point's coords ----
    if (t == (widx >> 3)) {
      const int psel = widx & 7;
      float gx = px[0], gy = py[0], gz = pz[0];
#pragma unroll
      for (int p = 1; p < PPT; ++p)
        if (psel == p) { gx = px[p]; gy = py[p]; gz = pz[p]; }
      redP[par][wv] = ((unsigned long long)wmaxu << 32) | (unsigned)(~widx);
      redC[par][wv] = make_float4(gx, gy, gz, 0.f);
    }
    __syncthreads();
    // ---- all threads: combine 8 wave candidates (broadcast LDS reads) ----
    ulonglong2 pA = *(const ulonglong2*)&redP[par][0];
    ulonglong2 pB = *(const ulonglong2*)&redP[par][2];
    ulonglong2 pC = *(const ulonglong2*)&redP[par][4];
    ulonglong2 pD = *(const ulonglong2*)&redP[par][6];
    float4 c0 = redC[par][0], c1 = redC[par][1], c2 = redC[par][2], c3 = redC[par][3];
    float4 c4 = redC[par][4], c5 = redC[par][5], c6 = redC[par][6], c7 = redC[par][7];
    unsigned long long q0 = pA.x > pA.y ? pA.x : pA.y;
    unsigned long long q1 = pB.x > pB.y ? pB.x : pB.y;
    unsigned long long q2 = pC.x > pC.y ? pC.x : pC.y;
    unsigned long long q3 = pD.x > pD.y ? pD.x : pD.y;
    unsigned long long r0 = q0 > q1 ? q0 : q1;
    unsigned long long r1 = q2 > q3 ? q2 : q3;
    unsigned long long win = r0 > r1 ? r0 : r1;
    const int fi = (int)(~(unsigned)win);   // global index of selected point
    const int ws = fi >> 9;                 // winning wave (512 idx per wave)
    float4 s0 = (ws & 1) ? c1 : c0;
    float4 s1 = (ws & 1) ? c3 : c2;
    float4 s2 = (ws & 1) ? c5 : c4;
    float4 s3 = (ws & 1) ? c7 : c6;
    float4 u0 = (ws & 2) ? s1 : s0;
    float4 u1 = (ws & 2) ? s3 : s2;
    float4 fc = (ws & 4) ? u1 : u0;
    lx = fc.x; ly = fc.y; lz = fc.z;
    if (t == 0) selidx[i] = fi;
  }
  __syncthreads();
  // epilogue: coalesced write of new_xyz to workspace + output
  for (int k = t; k < S_; k += 512) {
    int id = selidx[k];
    float x = sx[id*3], y = sx[id*3+1], z = sx[id*3+2];
    int o = (b * S_ + k) * 3;
    nxyz[o] = x; nxyz[o+1] = y; nxyz[o+2] = z;
    out_nxyz[o] = x; out_nxyz[o+1] = y; out_nxyz[o+2] = z;
  }
}

// ---------------------------------------------------------------------------
// K2: attention gate.
// ---------------------------------------------------------------------------
__global__ __launch_bounds__(256) void att_kernel(const float* __restrict__ nxyz,
    const float* __restrict__ w_att, const float* __restrict__ b_att,
    float* __restrict__ att) {
  __shared__ float ai[3 * S_];
  int b = blockIdx.x, t = threadIdx.x;
  for (int k = t; k < 3 * S_; k += 256) {
    int d = k >> 10, s = k & 1023;
    ai[k] = nxyz[(b * S_ + s) * 3 + d];
  }
  __syncthreads();
  float acc = b_att[t];
#pragma unroll 8
  for (int k = 0; k < 3 * S_; ++k)
    acc = fmaf(ai[k], w_att[k * 256 + t], acc);
  att[b * 256 + t] = 1.f / (1.f + expf(-acc));
}

// ---------------------------------------------------------------------------
// K3: fused dual-radius ball query (bit-exact d2 < r2; first-NS in index
// order; pad with first hit).
// ---------------------------------------------------------------------------
__global__ __launch_bounds__(256) void ballq2_kernel(const float4* __restrict__ xyzf,
    const float* __restrict__ nxyz, int* __restrict__ idx0buf, int* __restrict__ idx1buf) {
  const float r2a = (float)(0.2 * 0.2), r2b = (float)(0.4 * 0.4);
  int lane = threadIdx.x & 63;
  int cid = blockIdx.x * 4 + (threadIdx.x >> 6);
  int b = cid >> 10;
  float cx = nxyz[cid*3], cy = nxyz[cid*3+1], cz = nxyz[cid*3+2];
  const float4* xb = xyzf + b * N_;
  int cnt0 = 0, cnt1 = 0, first0 = 0, first1 = 0;
  const unsigned long long below = (1ull << lane) - 1ull;
  for (int base = 0; base < N_; base += 64) {
    float4 P = xb[base + lane];
    float dx = __fsub_rn(cx, P.x), dy = __fsub_rn(cy, P.y), dz = __fsub_rn(cz, P.z);
    float d2 = __fadd_rn(__fadd_rn(__fmul_rn(dx,dx), __fmul_rn(dy,dy)), __fmul_rn(dz,dz));
    bool h0 = d2 < r2a, h1 = d2 < r2b;
    unsigned long long m0 = __ballot(h0), m1 = __ballot(h1);
    if (cnt0 == 0 && m0 != 0ull) first0 = base + (int)__builtin_ctzll(m0);
    if (cnt1 == 0 && m1 != 0ull) first1 = base + (int)__builtin_ctzll(m1);
    if (h0) {
      int pos = cnt0 + (int)__popcll(m0 & below);
      if (pos < 32) idx0buf[cid * 32 + pos] = base + lane;
    }
    if (h1) {
      int pos = cnt1 + (int)__popcll(m1 & below);
      if (pos < 64) idx1buf[cid * 64 + pos] = base + lane;
    }
    cnt0 += (int)__popcll(m0);
    cnt1 += (int)__popcll(m1);
    if (cnt0 >= 32 && cnt1 >= 64) break;
  }
  if (cnt0 < 32)
    for (int p = cnt0 + lane; p < 32; p += 64) idx0buf[cid * 32 + p] = first0;
  if (cnt1 < 64)
    for (int p = cnt1 + lane; p < 64; p += 64) idx1buf[cid * 64 + p] = first1;
}

// ---------------------------------------------------------------------------
// K4: GEMM-tiled fused group + MLP + maxpool + attention + store.
// 256 threads (4 waves), 128 columns/block. og = t&15, cg = t>>4.
// ---------------------------------------------------------------------------
template<int NS>
__global__ __launch_bounds__(256, 4) void mlp_kernel(
    const float4* __restrict__ xyzf, const float* __restrict__ feats,
    const float* __restrict__ nxyz, const float* __restrict__ att,
    const int* __restrict__ idxbuf, const float* __restrict__ wt,
    float* __restrict__ outf, int g) {
  constexpr int NCEN = 128 / NS;
  constexpr int XS = 132;
  __shared__ float xs[67 * XS];
  float* red = xs;
  const int t = threadIdx.x;
  const int cid0 = blockIdx.x * NCEN;
  const int b = cid0 >> 10;

  {
    const int col = t & 127, h = t >> 7;
    const int cidg = cid0 + col / NS;
    const int j = col % NS;
    const int p = idxbuf[cidg * NS + j];
    if (h == 0) {
      float4 P = xyzf[b * N_ + p];
      xs[0*XS+col] = __fsub_rn(P.x, nxyz[cidg*3+0]);
      xs[1*XS+col] = __fsub_rn(P.y, nxyz[cidg*3+1]);
      xs[2*XS+col] = __fsub_rn(P.z, nxyz[cidg*3+2]);
    }
    const float4* f4 = (const float4*)(feats + (size_t)(b*N_+p)*64) + h*8;
#pragma unroll
    for (int q = 0; q < 8; ++q) {
      float4 u = f4[q];
      int r = 3 + h*32 + q*4;
      xs[(r+0)*XS+col]=u.x; xs[(r+1)*XS+col]=u.y; xs[(r+2)*XS+col]=u.z; xs[(r+3)*XS+col]=u.w;
    }
  }
  __syncthreads();

  const int og = t & 15, cg = t >> 4;
  const float* w0  = wt;
  const float* w1  = wt + 67*64;
  const float* w2  = w1 + 64*64;
  const float* bb0 = w2 + 64*128;
  const float* bb1 = bb0 + 64;
  const float* bb2 = bb1 + 64;

  float acc[4][8];

  // ---- layer 1: 67 -> 64 ----
  {
    float4 bv = *(const float4*)&bb0[og*4];
    float b4[4] = {bv.x, bv.y, bv.z, bv.w};
#pragma unroll
    for (int oo = 0; oo < 4; ++oo)
#pragma unroll
      for (int cc = 0; cc < 8; ++cc) acc[oo][cc] = b4[oo];
    for (int k = 0; k < 67; ++k) {
      float4 x0 = *(const float4*)&xs[k*XS + cg*8];
      float4 x1 = *(const float4*)&xs[k*XS + cg*8 + 4];
      float4 wv = *(const float4*)&w0[k*64 + og*4];
      float x8[8] = {x0.x,x0.y,x0.z,x0.w,x1.x,x1.y,x1.z,x1.w};
      float w4[4] = {wv.x,wv.y,wv.z,wv.w};
#pragma unroll
      for (int oo = 0; oo < 4; ++oo)
#pragma unroll
        for (int cc = 0; cc < 8; ++cc) acc[oo][cc] = fmaf(w4[oo], x8[cc], acc[oo][cc]);
    }
  }
  __syncthreads();
#pragma unroll
  for (int oo = 0; oo < 4; ++oo) {
    float4 y0, y1;
    y0.x=fmaxf(acc[oo][0],0.f); y0.y=fmaxf(acc[oo][1],0.f);
    y0.z=fmaxf(acc[oo][2],0.f); y0.w=fmaxf(acc[oo][3],0.f);
    y1.x=fmaxf(acc[oo][4],0.f); y1.y=fmaxf(acc[oo][5],0.f);
    y1.z=fmaxf(acc[oo][6],0.f); y1.w=fmaxf(acc[oo][7],0.f);
    *(float4*)&xs[(og*4+oo)*XS + cg*8]     = y0;
    *(float4*)&xs[(og*4+oo)*XS + cg*8 + 4] = y1;
  }
  __syncthreads();

  // ---- layer 2: 64 -> 64 ----
  {
    float4 bv = *(const float4*)&bb1[og*4];
    float b4[4] = {bv.x, bv.y, bv.z, bv.w};
#pragma unroll
    for (int oo = 0; oo < 4; ++oo)
#pragma unroll
      for (int cc = 0; cc < 8; ++cc) acc[oo][cc] = b4[oo];
    for (int k = 0; k < 64; ++k) {
      float4 x0 = *(const float4*)&xs[k*XS + cg*8];
      float4 x1 = *(const float4*)&xs[k*XS + cg*8 + 4];
      float4 wv = *(const float4*)&w1[k*64 + og*4];
      float x8[8] = {x0.x,x0.y,x0.z,x0.w,x1.x,x1.y,x1.z,x1.w};
      float w4[4] = {wv.x,wv.y,wv.z,wv.w};
#pragma unroll
      for (int oo = 0; oo < 4; ++oo)
#pragma unroll
        for (int cc = 0; cc < 8; ++cc) acc[oo][cc] = fmaf(w4[oo], x8[cc], acc[oo][cc]);
    }
  }
  __syncthreads();
#pragma unroll
  for (int oo = 0; oo < 4; ++oo) {
    float4 y0, y1;
    y0.x=fmaxf(acc[oo][0],0.f); y0.y=fmaxf(acc[oo][1],0.f);
    y0.z=fmaxf(acc[oo][2],0.f); y0.w=fmaxf(acc[oo][3],0.f);
    y1.x=fmaxf(acc[oo][4],0.f); y1.y=fmaxf(acc[oo][5],0.f);
    y1.z=fmaxf(acc[oo][6],0.f); y1.w=fmaxf(acc[oo][7],0.f);
    *(float4*)&xs[(og*4+oo)*XS + cg*8]     = y0;
    *(float4*)&xs[(og*4+oo)*XS + cg*8 + 4] = y1;
  }
  __syncthreads();

  // ---- layer 3: 64 -> 128, ReLU + in-register partial maxpool ----
  float acc3[8][8];
  {
    float4 b0v = *(const float4*)&bb2[og*8];
    float4 b1v = *(const float4*)&bb2[og*8 + 4];
    float b8[8] = {b0v.x,b0v.y,b0v.z,b0v.w,b1v.x,b1v.y,b1v.z,b1v.w};
#pragma unroll
    for (int oo = 0; oo < 8; ++oo)
#pragma unroll
      for (int cc = 0; cc < 8; ++cc) acc3[oo][cc] = b8[oo];
    for (int k = 0; k < 64; ++k) {
      float4 x0 = *(const float4*)&xs[k*XS + cg*8];
      float4 x1 = *(const float4*)&xs[k*XS + cg*8 + 4];
      float4 wa = *(const float4*)&w2[k*128 + og*8];
      float4 wb = *(const float4*)&w2[k*128 + og*8 + 4];
      float x8[8] = {x0.x,x0.y,x0.z,x0.w,x1.x,x1.y,x1.z,x1.w};
      float w8[8] = {wa.x,wa.y,wa.z,wa.w,wb.x,wb.y,wb.z,wb.w};
#pragma unroll
      for (int oo = 0; oo < 8; ++oo)
#pragma unroll
        for (int cc = 0; cc < 8; ++cc) acc3[oo][cc] = fmaf(w8[oo], x8[cc], acc3[oo][cc]);
    }
  }
  float pm[8];
#pragma unroll
  for (int oo = 0; oo < 8; ++oo) {
    float v = fmaxf(acc3[oo][0], 0.f);
#pragma unroll
    for (int cc = 1; cc < 8; ++cc) v = fmaxf(v, fmaxf(acc3[oo][cc], 0.f));
    pm[oo] = v;
  }
#pragma unroll
  for (int oo = 0; oo < 8; ++oo) {
    pm[oo] = fmaxf(pm[oo], __shfl_xor(pm[oo], 16));
    pm[oo] = fmaxf(pm[oo], __shfl_xor(pm[oo], 32));
  }
  __syncthreads();
  if ((t & 63) < 16) {
    int w = t >> 6;
#pragma unroll
    for (int oo = 0; oo < 8; ++oo) red[w*128 + og*8 + oo] = pm[oo];
  }
  __syncthreads();

  const int ch = t & 127;
  const float a = att[b*256 + g*128 + ch];
  if (NS == 64) {
    int c = t >> 7;
    float v = fmaxf(red[(2*c)*128 + ch], red[(2*c+1)*128 + ch]);
    int s = (cid0 + c) & 1023;
    outf[((size_t)(b*256 + g*128 + ch)) * 1024 + s] = v * a;
  } else {
#pragma unroll
    for (int kk = 0; kk < 2; ++kk) {
      int c = (t >> 7) * 2 + kk;
      float v = red[c*128 + ch];
      int s = (cid0 + c) & 1023;
      outf[((size_t)(b*256 + g*128 + ch)) * 1024 + s] = v * a;
    }
  }
}

// ---------------------------------------------------------------------------
extern "C" void kernel_launch(void* const* d_in, const int* in_sizes, int n_in,
                              void* d_out, int out_size, void* d_ws, size_t ws_size,
                              hipStream_t stream) {
  const float* xyz   = (const float*)d_in[0];
  const float* feats = (const float*)d_in[1];
  const float* w_att = (const float*)d_in[2];
  const float* b_att = (const float*)d_in[3];
  const float* w00 = (const float*)d_in[4];
  const float* b00 = (const float*)d_in[5];
  const float* w01 = (const float*)d_in[6];
  const float* b01 = (const float*)d_in[7];
  const float* w02 = (const float*)d_in[8];
  const float* b02 = (const float*)d_in[9];
  const float* w10 = (const float*)d_in[10];
  const float* b10 = (const float*)d_in[11];
  const float* w11 = (const float*)d_in[12];
  const float* b11 = (const float*)d_in[13];
  const float* w12 = (const float*)d_in[14];
  const float* b12 = (const float*)d_in[15];

  float* wsf = (float*)d_ws;
  int*   wsi = (int*)d_ws;
  float4* xyzf = (float4*)(wsf + WS_XYZF);
  float* nxyz  = wsf + WS_NXYZ;
  float* att   = wsf + WS_ATT;
  float* wt    = wsf + WS_WT;
  int* idx0 = wsi + WS_IDX0;
  int* idx1 = wsi + WS_IDX1;

  float* out  = (float*)d_out;
  float* outf = out + B_ * S_ * 3;

  int cvt_total = B_*N_ + 2*WT_G;
  hipLaunchKernelGGL(convert_kernel, dim3((cvt_total + 255) / 256), dim3(256), 0, stream,
                     xyz, w00, w01, w02, b00, b01, b02, w10, w11, w12, b10, b11, b12,
                     xyzf, wt);
  hipLaunchKernelGGL(fps_kernel, dim3(B_), dim3(512), 0, stream, xyzf, nxyz, out);
  hipLaunchKernelGGL(att_kernel, dim3(B_), dim3(256), 0, stream, nxyz, w_att, b_att, att);
  hipLaunchKernelGGL(ballq2_kernel, dim3(B_*S_/4), dim3(256), 0, stream,
                     xyzf, nxyz, idx0, idx1);
  hipLaunchKernelGGL((mlp_kernel<32>), dim3(B_*S_*32/128), dim3(256), 0, stream,
                     xyzf, feats, nxyz, att, idx0, wt, outf, 0);
  hipLaunchKernelGGL((mlp_kernel<64>), dim3(B_*S_*64/128), dim3(256), 0, stream,
                     xyzf, feats, nxyz, att, idx1, wt + WT_G, outf, 1);
}

// Round 7
// 1743.087 us; speedup vs baseline: 10.8974x; 1.0643x over previous
//
#include <hip/hip_runtime.h>
#include <cstdint>
#include <cstddef>

// ---------------------------------------------------------------------------
// PointNet++ SA module (multi-scale grouping) with attention gate.
// B=16, N=4096, C_IN=64, NPOINT=1024, radii (0.2,0.4), nsamples (32,64),
// MLPs ((64,64,128),(64,64,128)), C_TOTAL=256. Inputs f32, output f32.
// Round 7: FPS at 256 threads (4 waves, 1 wave/SIMD) x 16 pts/thread —
// halves the duplicated per-wave overhead that round 6's counters showed was
// the issue-bound cost (VALUBusy 62% of active-CU ceiling). Max-tree local
// argmax, 4-candidate combine. MLP/ballq/att unchanged (MLP is near its f32
// FMA floor; bf16 MFMA would risk the 0.039 absmax budget).
// ---------------------------------------------------------------------------

constexpr int B_ = 16, N_ = 4096, S_ = 1024;
constexpr int WT_G = 67*64 + 64*64 + 128*64 + 64 + 64 + 128; // 16832 floats/group

// workspace layout in 4-byte units
constexpr int WS_XYZF = 0;                       // float4[B*N]
constexpr int WS_NXYZ = B_*N_*4;                 // float[B*S*3]
constexpr int WS_ATT  = WS_NXYZ + B_*S_*3;       // float[B*256]
constexpr int WS_WT   = WS_ATT + B_*256;         // float[2*WT_G]
constexpr int WS_IDX0 = WS_WT + 2*WT_G;          // int[B*S*32]
constexpr int WS_IDX1 = WS_IDX0 + B_*S_*32;      // int[B*S*64]

// ---------------------------------------------------------------------------
// K0: xyz -> float4 padding; weights transposed to [cin][cout].
// ---------------------------------------------------------------------------
__global__ __launch_bounds__(256) void convert_kernel(
    const float* __restrict__ xyz,
    const float* __restrict__ w00, const float* __restrict__ w01,
    const float* __restrict__ w02, const float* __restrict__ b00,
    const float* __restrict__ b01, const float* __restrict__ b02,
    const float* __restrict__ w10, const float* __restrict__ w11,
    const float* __restrict__ w12, const float* __restrict__ b10,
    const float* __restrict__ b11, const float* __restrict__ b12,
    float4* __restrict__ xyzf, float* __restrict__ wt) {
  int id = blockIdx.x * 256 + threadIdx.x;
  if (id < B_*N_) {
    float4 v;
    v.x = xyz[id*3+0]; v.y = xyz[id*3+1]; v.z = xyz[id*3+2]; v.w = 0.f;
    xyzf[id] = v;
    return;
  }
  int wid = id - B_*N_;
  if (wid >= 2*WT_G) return;
  int g = wid / WT_G, r = wid % WT_G;
  float val;
  if (r < 4288) {                    // layer0: w (64,67) -> wt0[c*64+o]
    int c = r >> 6, o = r & 63;
    val = (g ? w10 : w00)[o*67 + c];
  } else if (r < 8384) {             // layer1: w (64,64) -> wt1[c*64+o]
    int rr = r - 4288; int c = rr >> 6, o = rr & 63;
    val = (g ? w11 : w01)[o*64 + c];
  } else if (r < 16576) {            // layer2: w (128,64) -> wt2[c*128+o]
    int rr = r - 8384; int c = rr >> 7, o = rr & 127;
    val = (g ? w12 : w02)[o*64 + c];
  } else {                           // biases
    int rr = r - 16576;
    val = (rr < 64)  ? (g ? b10 : b00)[rr]
        : (rr < 128) ? (g ? b11 : b01)[rr - 64]
                     : (g ? b12 : b02)[rr - 128];
  }
  wt[g*WT_G + r] = val;
}

// ---------------------------------------------------------------------------
// K1: furthest point sampling. One block/batch, 256 thr (4 waves) x 16 pts.
// Per iteration: no-FMA f32 distance+min update (bit-exact vs np), max-tree
// local argmax + reverse == scan (smallest p), DPP uint wave max,
// ballot+ctz+readlane smallest index, winner forwards coords + (val,~idx)
// key to double-buffered LDS, ONE barrier, all threads combine 4 candidates
// (u64 max tree, lexicographic => np-exact) + 2-level coord select.
// ---------------------------------------------------------------------------
__global__ __launch_bounds__(256) void fps_kernel(const float4* __restrict__ xyzf,
    float* __restrict__ nxyz, float* __restrict__ out_nxyz) {
  constexpr int PPT = 16;
  __shared__ float sx[N_*3];
  __shared__ int   selidx[S_];
  __shared__ alignas(16) unsigned long long redP[2][4];
  __shared__ alignas(16) float4 redC[2][4];
  const int b = blockIdx.x, t = threadIdx.x;
  const int wv = t >> 6;  // wave id 0..3
  const float4* xb = xyzf + b * N_;
  float px[PPT], py[PPT], pz[PPT], m[PPT];
#pragma unroll
  for (int p = 0; p < PPT; ++p) {
    int idx = t * PPT + p;
    float4 v = xb[idx];
    px[p] = v.x; py[p] = v.y; pz[p] = v.z; m[p] = 1e10f;
    sx[idx*3+0] = v.x; sx[idx*3+1] = v.y; sx[idx*3+2] = v.z;
  }
  if (t == 0) selidx[0] = 0;   // first sampled index is 0 (matches reference)
  __syncthreads();
  float lx = sx[0], ly = sx[1], lz = sx[2];
  for (int i = 1; i < S_; ++i) {
    // ---- distance + running-min update (bit-exact np arithmetic) ----
#pragma unroll
    for (int p = 0; p < PPT; ++p) {
      float dx = __fsub_rn(px[p], lx), dy = __fsub_rn(py[p], ly), dz = __fsub_rn(pz[p], lz);
      float d = __fadd_rn(__fadd_rn(__fmul_rn(dx,dx), __fmul_rn(dy,dy)), __fmul_rn(dz,dz));
      m[p] = fminf(m[p], d);
    }
    // ---- local argmax: max tree (v_max3 fusion) + reverse == scan ----
    float h0 = fmaxf(fmaxf(m[0],  m[1]),  fmaxf(m[2],  m[3]));
    float h1 = fmaxf(fmaxf(m[4],  m[5]),  fmaxf(m[6],  m[7]));
    float h2 = fmaxf(fmaxf(m[8],  m[9]),  fmaxf(m[10], m[11]));
    float h3 = fmaxf(fmaxf(m[12], m[13]), fmaxf(m[14], m[15]));
    float bv = fmaxf(fmaxf(h0, h1), fmaxf(h2, h3));
    int bp = PPT - 1;
#pragma unroll
    for (int p = PPT - 2; p >= 0; --p)
      if (m[p] == bv) bp = p;           // ends at smallest p attaining bv
    const int bi = t * PPT + bp;
    // ---- wave max via DPP (uint compare valid: all m >= 0, no NaN) ----
    unsigned vm = __float_as_uint(bv);
#define DPP_MAX(ctrl) { unsigned o = (unsigned)__builtin_amdgcn_update_dpp((int)vm, (int)vm, (ctrl), 0xf, 0xf, false); vm = vm > o ? vm : o; }
    DPP_MAX(0x111)  // row_shr:1
    DPP_MAX(0x112)  // row_shr:2
    DPP_MAX(0x114)  // row_shr:4
    DPP_MAX(0x118)  // row_shr:8
    DPP_MAX(0x142)  // row_bcast:15
    DPP_MAX(0x143)  // row_bcast:31
#undef DPP_MAX
    const unsigned wmaxu = (unsigned)__builtin_amdgcn_readlane((int)vm, 63);
    // smallest index attaining the wave max: lanes are index-ordered
    const unsigned long long mk = __ballot(__float_as_uint(bv) == wmaxu);
    const int fl = (int)__builtin_ctzll(mk);
    const int widx = __builtin_amdgcn_readlane(bi, fl);
    const int par = i & 1;
    // ---- winner lane forwards packed key + its point's coords ----
    if (t == (widx >> 4)) {
      const int psel = widx & 15;
      float gx = px[0], gy = py[0], gz = pz[0];
#pragma unroll
      for (int p = 1; p < PPT; ++p)
        if (psel == p) { gx = px[p]; gy = py[p]; gz = pz[p]; }
      redP[par][wv] = ((unsigned long long)wmaxu << 32) | (unsigned)(~widx);
      redC[par][wv] = make_float4(gx, gy, gz, 0.f);
    }
    __syncthreads();
    // ---- all threads: combine 4 wave candidates (broadcast LDS reads) ----
    ulonglong2 pA = *(const ulonglong2*)&redP[par][0];
    ulonglong2 pB = *(const ulonglong2*)&redP[par][2];
    float4 c0 = redC[par][0], c1 = redC[par][1];
    float4 c2 = redC[par][2], c3 = redC[par][3];
    unsigned long long q0 = pA.x > pA.y ? pA.x : pA.y;
    unsigned long long q1 = pB.x > pB.y ? pB.x : pB.y;
    unsigned long long win = q0 > q1 ? q0 : q1;
    const int fi = (int)(~(unsigned)win);   // global index of selected point
    const int ws = fi >> 10;                // winning wave (1024 idx per wave)
    float4 s0 = (ws & 1) ? c1 : c0;
    float4 s1 = (ws & 1) ? c3 : c2;
    float4 fc = (ws & 2) ? s1 : s0;
    lx = fc.x; ly = fc.y; lz = fc.z;
    if (t == 0) selidx[i] = fi;
  }
  __syncthreads();
  // epilogue: coalesced write of new_xyz to workspace + output
  for (int k = t; k < S_; k += 256) {
    int id = selidx[k];
    float x = sx[id*3], y = sx[id*3+1], z = sx[id*3+2];
    int o = (b * S_ + k) * 3;
    nxyz[o] = x; nxyz[o+1] = y; nxyz[o+2] = z;
    out_nxyz[o] = x; out_nxyz[o+1] = y; out_nxyz[o+2] = z;
  }
}

// ---------------------------------------------------------------------------
// K2: attention gate.
// ---------------------------------------------------------------------------
__global__ __launch_bounds__(256) void att_kernel(const float* __restrict__ nxyz,
    const float* __restrict__ w_att, const float* __restrict__ b_att,
    float* __restrict__ att) {
  __shared__ float ai[3 * S_];
  int b = blockIdx.x, t = threadIdx.x;
  for (int k = t; k < 3 * S_; k += 256) {
    int d = k >> 10, s = k & 1023;
    ai[k] = nxyz[(b * S_ + s) * 3 + d];
  }
  __syncthreads();
  float acc = b_att[t];
#pragma unroll 8
  for (int k = 0; k < 3 * S_; ++k)
    acc = fmaf(ai[k], w_att[k * 256 + t], acc);
  att[b * 256 + t] = 1.f / (1.f + expf(-acc));
}

// ---------------------------------------------------------------------------
// K3: fused dual-radius ball query (bit-exact d2 < r2; first-NS in index
// order; pad with first hit).
// ---------------------------------------------------------------------------
__global__ __launch_bounds__(256) void ballq2_kernel(const float4* __restrict__ xyzf,
    const float* __restrict__ nxyz, int* __restrict__ idx0buf, int* __restrict__ idx1buf) {
  const float r2a = (float)(0.2 * 0.2), r2b = (float)(0.4 * 0.4);
  int lane = threadIdx.x & 63;
  int cid = blockIdx.x * 4 + (threadIdx.x >> 6);
  int b = cid >> 10;
  float cx = nxyz[cid*3], cy = nxyz[cid*3+1], cz = nxyz[cid*3+2];
  const float4* xb = xyzf + b * N_;
  int cnt0 = 0, cnt1 = 0, first0 = 0, first1 = 0;
  const unsigned long long below = (1ull << lane) - 1ull;
  for (int base = 0; base < N_; base += 64) {
    float4 P = xb[base + lane];
    float dx = __fsub_rn(cx, P.x), dy = __fsub_rn(cy, P.y), dz = __fsub_rn(cz, P.z);
    float d2 = __fadd_rn(__fadd_rn(__fmul_rn(dx,dx), __fmul_rn(dy,dy)), __fmul_rn(dz,dz));
    bool h0 = d2 < r2a, h1 = d2 < r2b;
    unsigned long long m0 = __ballot(h0), m1 = __ballot(h1);
    if (cnt0 == 0 && m0 != 0ull) first0 = base + (int)__builtin_ctzll(m0);
    if (cnt1 == 0 && m1 != 0ull) first1 = base + (int)__builtin_ctzll(m1);
    if (h0) {
      int pos = cnt0 + (int)__popcll(m0 & below);
      if (pos < 32) idx0buf[cid * 32 + pos] = base + lane;
    }
    if (h1) {
      int pos = cnt1 + (int)__popcll(m1 & below);
      if (pos < 64) idx1buf[cid * 64 + pos] = base + lane;
    }
    cnt0 += (int)__popcll(m0);
    cnt1 += (int)__popcll(m1);
    if (cnt0 >= 32 && cnt1 >= 64) break;
  }
  if (cnt0 < 32)
    for (int p = cnt0 + lane; p < 32; p += 64) idx0buf[cid * 32 + p] = first0;
  if (cnt1 < 64)
    for (int p = cnt1 + lane; p < 64; p += 64) idx1buf[cid * 64 + p] = first1;
}

// ---------------------------------------------------------------------------
// K4: GEMM-tiled fused group + MLP + maxpool + attention + store.
// 256 threads (4 waves), 128 columns/block. og = t&15, cg = t>>4.
// ---------------------------------------------------------------------------
template<int NS>
__global__ __launch_bounds__(256, 4) void mlp_kernel(
    const float4* __restrict__ xyzf, const float* __restrict__ feats,
    const float* __restrict__ nxyz, const float* __restrict__ att,
    const int* __restrict__ idxbuf, const float* __restrict__ wt,
    float* __restrict__ outf, int g) {
  constexpr int NCEN = 128 / NS;
  constexpr int XS = 132;
  __shared__ float xs[67 * XS];
  float* red = xs;
  const int t = threadIdx.x;
  const int cid0 = blockIdx.x * NCEN;
  const int b = cid0 >> 10;

  {
    const int col = t & 127, h = t >> 7;
    const int cidg = cid0 + col / NS;
    const int j = col % NS;
    const int p = idxbuf[cidg * NS + j];
    if (h == 0) {
      float4 P = xyzf[b * N_ + p];
      xs[0*XS+col] = __fsub_rn(P.x, nxyz[cidg*3+0]);
      xs[1*XS+col] = __fsub_rn(P.y, nxyz[cidg*3+1]);
      xs[2*XS+col] = __fsub_rn(P.z, nxyz[cidg*3+2]);
    }
    const float4* f4 = (const float4*)(feats + (size_t)(b*N_+p)*64) + h*8;
#pragma unroll
    for (int q = 0; q < 8; ++q) {
      float4 u = f4[q];
      int r = 3 + h*32 + q*4;
      xs[(r+0)*XS+col]=u.x; xs[(r+1)*XS+col]=u.y; xs[(r+2)*XS+col]=u.z; xs[(r+3)*XS+col]=u.w;
    }
  }
  __syncthreads();

  const int og = t & 15, cg = t >> 4;
  const float* w0  = wt;
  const float* w1  = wt + 67*64;
  const float* w2  = w1 + 64*64;
  const float* bb0 = w2 + 64*128;
  const float* bb1 = bb0 + 64;
  const float* bb2 = bb1 + 64;

  float acc[4][8];

  // ---- layer 1: 67 -> 64 ----
  {
    float4 bv = *(const float4*)&bb0[og*4];
    float b4[4] = {bv.x, bv.y, bv.z, bv.w};
#pragma unroll
    for (int oo = 0; oo < 4; ++oo)
#pragma unroll
      for (int cc = 0; cc < 8; ++cc) acc[oo][cc] = b4[oo];
    for (int k = 0; k < 67; ++k) {
      float4 x0 = *(const float4*)&xs[k*XS + cg*8];
      float4 x1 = *(const float4*)&xs[k*XS + cg*8 + 4];
      float4 wv = *(const float4*)&w0[k*64 + og*4];
      float x8[8] = {x0.x,x0.y,x0.z,x0.w,x1.x,x1.y,x1.z,x1.w};
      float w4[4] = {wv.x,wv.y,wv.z,wv.w};
#pragma unroll
      for (int oo = 0; oo < 4; ++oo)
#pragma unroll
        for (int cc = 0; cc < 8; ++cc) acc[oo][cc] = fmaf(w4[oo], x8[cc], acc[oo][cc]);
    }
  }
  __syncthreads();
#pragma unroll
  for (int oo = 0; oo < 4; ++oo) {
    float4 y0, y1;
    y0.x=fmaxf(acc[oo][0],0.f); y0.y=fmaxf(acc[oo][1],0.f);
    y0.z=fmaxf(acc[oo][2],0.f); y0.w=fmaxf(acc[oo][3],0.f);
    y1.x=fmaxf(acc[oo][4],0.f); y1.y=fmaxf(acc[oo][5],0.f);
    y1.z=fmaxf(acc[oo][6],0.f); y1.w=fmaxf(acc[oo][7],0.f);
    *(float4*)&xs[(og*4+oo)*XS + cg*8]     = y0;
    *(float4*)&xs[(og*4+oo)*XS + cg*8 + 4] = y1;
  }
  __syncthreads();

  // ---- layer 2: 64 -> 64 ----
  {
    float4 bv = *(const float4*)&bb1[og*4];
    float b4[4] = {bv.x, bv.y, bv.z, bv.w};
#pragma unroll
    for (int oo = 0; oo < 4; ++oo)
#pragma unroll
      for (int cc = 0; cc < 8; ++cc) acc[oo][cc] = b4[oo];
    for (int k = 0; k < 64; ++k) {
      float4 x0 = *(const float4*)&xs[k*XS + cg*8];
      float4 x1 = *(const float4*)&xs[k*XS + cg*8 + 4];
      float4 wv = *(const float4*)&w1[k*64 + og*4];
      float x8[8] = {x0.x,x0.y,x0.z,x0.w,x1.x,x1.y,x1.z,x1.w};
      float w4[4] = {wv.x,wv.y,wv.z,wv.w};
#pragma unroll
      for (int oo = 0; oo < 4; ++oo)
#pragma unroll
        for (int cc = 0; cc < 8; ++cc) acc[oo][cc] = fmaf(w4[oo], x8[cc], acc[oo][cc]);
    }
  }
  __syncthreads();
#pragma unroll
  for (int oo = 0; oo < 4; ++oo) {
    float4 y0, y1;
    y0.x=fmaxf(acc[oo][0],0.f); y0.y=fmaxf(acc[oo][1],0.f);
    y0.z=fmaxf(acc[oo][2],0.f); y0.w=fmaxf(acc[oo][3],0.f);
    y1.x=fmaxf(acc[oo][4],0.f); y1.y=fmaxf(acc[oo][5],0.f);
    y1.z=fmaxf(acc[oo][6],0.f); y1.w=fmaxf(acc[oo][7],0.f);
    *(float4*)&xs[(og*4+oo)*XS + cg*8]     = y0;
    *(float4*)&xs[(og*4+oo)*XS + cg*8 + 4] = y1;
  }
  __syncthreads();

  // ---- layer 3: 64 -> 128, ReLU + in-register partial maxpool ----
  float acc3[8][8];
  {
    float4 b0v = *(const float4*)&bb2[og*8];
    float4 b1v = *(const float4*)&bb2[og*8 + 4];
    float b8[8] = {b0v.x,b0v.y,b0v.z,b0v.w,b1v.x,b1v.y,b1v.z,b1v.w};
#pragma unroll
    for (int oo = 0; oo < 8; ++oo)
#pragma unroll
      for (int cc = 0; cc < 8; ++cc) acc3[oo][cc] = b8[oo];
    for (int k = 0; k < 64; ++k) {
      float4 x0 = *(const float4*)&xs[k*XS + cg*8];
      float4 x1 = *(const float4*)&xs[k*XS + cg*8 + 4];
      float4 wa = *(const float4*)&w2[k*128 + og*8];
      float4 wb = *(const float4*)&w2[k*128 + og*8 + 4];
      float x8[8] = {x0.x,x0.y,x0.z,x0.w,x1.x,x1.y,x1.z,x1.w};
      float w8[8] = {wa.x,wa.y,wa.z,wa.w,wb.x,wb.y,wb.z,wb.w};
#pragma unroll
      for (int oo = 0; oo < 8; ++oo)
#pragma unroll
        for (int cc = 0; cc < 8; ++cc) acc3[oo][cc] = fmaf(w8[oo], x8[cc], acc3[oo][cc]);
    }
  }
  float pm[8];
#pragma unroll
  for (int oo = 0; oo < 8; ++oo) {
    float v = fmaxf(acc3[oo][0], 0.f);
#pragma unroll
    for (int cc = 1; cc < 8; ++cc) v = fmaxf(v, fmaxf(acc3[oo][cc], 0.f));
    pm[oo] = v;
  }
#pragma unroll
  for (int oo = 0; oo < 8; ++oo) {
    pm[oo] = fmaxf(pm[oo], __shfl_xor(pm[oo], 16));
    pm[oo] = fmaxf(pm[oo], __shfl_xor(pm[oo], 32));
  }
  __syncthreads();
  if ((t & 63) < 16) {
    int w = t >> 6;
#pragma unroll
    for (int oo = 0; oo < 8; ++oo) red[w*128 + og*8 + oo] = pm[oo];
  }
  __syncthreads();

  const int ch = t & 127;
  const float a = att[b*256 + g*128 + ch];
  if (NS == 64) {
    int c = t >> 7;
    float v = fmaxf(red[(2*c)*128 + ch], red[(2*c+1)*128 + ch]);
    int s = (cid0 + c) & 1023;
    outf[((size_t)(b*256 + g*128 + ch)) * 1024 + s] = v * a;
  } else {
#pragma unroll
    for (int kk = 0; kk < 2; ++kk) {
      int c = (t >> 7) * 2 + kk;
      float v = red[c*128 + ch];
      int s = (cid0 + c) & 1023;
      outf[((size_t)(b*256 + g*128 + ch)) * 1024 + s] = v * a;
    }
  }
}

// ---------------------------------------------------------------------------
extern "C" void kernel_launch(void* const* d_in, const int* in_sizes, int n_in,
                              void* d_out, int out_size, void* d_ws, size_t ws_size,
                              hipStream_t stream) {
  const float* xyz   = (const float*)d_in[0];
  const float* feats = (const float*)d_in[1];
  const float* w_att = (const float*)d_in[2];
  const float* b_att = (const float*)d_in[3];
  const float* w00 = (const float*)d_in[4];
  const float* b00 = (const float*)d_in[5];
  const float* w01 = (const float*)d_in[6];
  const float* b01 = (const float*)d_in[7];
  const float* w02 = (const float*)d_in[8];
  const float* b02 = (const float*)d_in[9];
  const float* w10 = (const float*)d_in[10];
  const float* b10 = (const float*)d_in[11];
  const float* w11 = (const float*)d_in[12];
  const float* b11 = (const float*)d_in[13];
  const float* w12 = (const float*)d_in[14];
  const float* b12 = (const float*)d_in[15];

  float* wsf = (float*)d_ws;
  int*   wsi = (int*)d_ws;
  float4* xyzf = (float4*)(wsf + WS_XYZF);
  float* nxyz  = wsf + WS_NXYZ;
  float* att   = wsf + WS_ATT;
  float* wt    = wsf + WS_WT;
  int* idx0 = wsi + WS_IDX0;
  int* idx1 = wsi + WS_IDX1;

  float* out  = (float*)d_out;
  float* outf = out + B_ * S_ * 3;

  int cvt_total = B_*N_ + 2*WT_G;
  hipLaunchKernelGGL(convert_kernel, dim3((cvt_total + 255) / 256), dim3(256), 0, stream,
                     xyz, w00, w01, w02, b00, b01, b02, w10, w11, w12, b10, b11, b12,
                     xyzf, wt);
  hipLaunchKernelGGL(fps_kernel, dim3(B_), dim3(256), 0, stream, xyzf, nxyz, out);
  hipLaunchKernelGGL(att_kernel, dim3(B_), dim3(256), 0, stream, nxyz, w_att, b_att, att);
  hipLaunchKernelGGL(ballq2_kernel, dim3(B_*S_/4), dim3(256), 0, stream,
                     xyzf, nxyz, idx0, idx1);
  hipLaunchKernelGGL((mlp_kernel<32>), dim3(B_*S_*32/128), dim3(256), 0, stream,
                     xyzf, feats, nxyz, att, idx0, wt, outf, 0);
  hipLaunchKernelGGL((mlp_kernel<64>), dim3(B_*S_*64/128), dim3(256), 0, stream,
                     xyzf, feats, nxyz, att, idx1, wt + WT_G, outf, 1);
}